// Round 1
// baseline (2983.357 us; speedup 1.0000x reference)
//
#include <hip/hip_runtime.h>
#include <hip/hip_bf16.h>

#define BATCH 8
#define SEQ   2048
#define DM    256
#define DI    512
#define DS    16
#define DTR   16
#define NL    4
#define ROWS  (BATCH*SEQ)   // 16384

// ---------- dtype-flexible load helpers ----------
__device__ __forceinline__ float bf2f(unsigned short u) {
    union { unsigned int i; float f; } v; v.i = ((unsigned int)u) << 16; return v.f;
}
__device__ __forceinline__ float ldg1(const void* p, int i, int bf) {
    if (bf) return bf2f(((const unsigned short*)p)[i]);
    return ((const float*)p)[i];
}
__device__ __forceinline__ float4 ldg4(const void* p, int i, int bf) { // i % 4 == 0
    if (bf) {
        ushort4 q = *(const ushort4*)(((const unsigned short*)p) + i);
        return make_float4(bf2f(q.x), bf2f(q.y), bf2f(q.z), bf2f(q.w));
    }
    return *(const float4*)(((const float*)p) + i);
}

// ---------- K0: dtype probe ----------
// If storage is bf16, ushort[2t] are true N(0,1)-scale values (|v| < 32).
// If storage is f32, ushort[2t] are f32 low-mantissa halves -> ~half have |v|>32.
__global__ void k_probe(const void* x, int* flag) {
    int t = threadIdx.x;  // 64 threads
    float v = bf2f(((const unsigned short*)x)[2 * t]);
    int bad = (fabsf(v) < 32.0f) ? 0 : 1;  // NaN -> bad
    for (int o = 1; o < 64; o <<= 1) bad += __shfl_xor(bad, o);
    if (t == 0) *flag = (bad > 8) ? 0 : 1;  // 0 = f32, 1 = bf16
}

// ---------- K1: input projection  h = x @ w_in^T + b_in ----------
__global__ __launch_bounds__(256) void k_inproj(const void* x, const void* w_in,
                                                const void* b_in, float* h, const int* flag) {
    int bf = *flag;
    int row = blockIdx.x, e = threadIdx.x;
    float x0 = ldg1(x, row * 2 + 0, bf), x1 = ldg1(x, row * 2 + 1, bf);
    float w0 = ldg1(w_in, e * 2 + 0, bf), w1 = ldg1(w_in, e * 2 + 1, bf);
    float bb = ldg1(b_in, e, bf);
    h[(size_t)row * DM + e] = fmaf(x0, w0, fmaf(x1, w1, bb));
}

// ---------- K2: rmsnorm ----------
__global__ __launch_bounds__(256) void k_rmsnorm(const float* h, const void* norm_w,
                                                 int w_off, float* xn, const int* flag) {
    int bf = *flag;
    int wv = threadIdx.x >> 6, ln = threadIdx.x & 63;
    int row = blockIdx.x * 4 + wv;
    float4 v = *(const float4*)(h + (size_t)row * DM + ln * 4);
    float ss = v.x * v.x + v.y * v.y + v.z * v.z + v.w * v.w;
    for (int o = 1; o < 64; o <<= 1) ss += __shfl_xor(ss, o);
    float sc = rsqrtf(ss / DM + 1e-5f);
    float4 w = ldg4(norm_w, w_off + ln * 4, bf);
    float4 o;
    o.x = v.x * sc * w.x; o.y = v.y * sc * w.y; o.z = v.z * sc * w.z; o.w = v.w * sc * w.w;
    *(float4*)(xn + (size_t)row * DM + ln * 4) = o;
}

// ---------- K3/K8: tiled fp32 GEMM  C[M,N] (+)= A[M,K] @ W[N,K]^T ----------
template <bool ADD>
__global__ __launch_bounds__(256) void k_gemm64(const float* A, const void* W, int w_off,
                                                float* C, int N, int K, const int* flag) {
    int bf = *flag;
    __shared__ float As[16][68];
    __shared__ float Ws[16][68];
    int bn = blockIdx.x, bm = blockIdx.y;
    int t = threadIdx.x;
    int lr = t >> 2, lk = (t & 3) * 4;
    const float* Arow = A + (size_t)(bm * 64 + lr) * K + lk;
    int wbase = w_off + (bn * 64 + lr) * K + lk;
    int ty = t >> 4, tx = t & 15;
    float acc[4][4] = {};
    for (int k0 = 0; k0 < K; k0 += 16) {
        float4 a = *(const float4*)(Arow + k0);
        float4 w = ldg4(W, wbase + k0, bf);
        __syncthreads();
        As[lk + 0][lr] = a.x; As[lk + 1][lr] = a.y; As[lk + 2][lr] = a.z; As[lk + 3][lr] = a.w;
        Ws[lk + 0][lr] = w.x; Ws[lk + 1][lr] = w.y; Ws[lk + 2][lr] = w.z; Ws[lk + 3][lr] = w.w;
        __syncthreads();
#pragma unroll
        for (int kk = 0; kk < 16; kk++) {
            float4 av = *(const float4*)&As[kk][ty * 4];
            float4 wv = *(const float4*)&Ws[kk][tx * 4];
            acc[0][0] = fmaf(av.x, wv.x, acc[0][0]); acc[0][1] = fmaf(av.x, wv.y, acc[0][1]);
            acc[0][2] = fmaf(av.x, wv.z, acc[0][2]); acc[0][3] = fmaf(av.x, wv.w, acc[0][3]);
            acc[1][0] = fmaf(av.y, wv.x, acc[1][0]); acc[1][1] = fmaf(av.y, wv.y, acc[1][1]);
            acc[1][2] = fmaf(av.y, wv.z, acc[1][2]); acc[1][3] = fmaf(av.y, wv.w, acc[1][3]);
            acc[2][0] = fmaf(av.z, wv.x, acc[2][0]); acc[2][1] = fmaf(av.z, wv.y, acc[2][1]);
            acc[2][2] = fmaf(av.z, wv.z, acc[2][2]); acc[2][3] = fmaf(av.z, wv.w, acc[2][3]);
            acc[3][0] = fmaf(av.w, wv.x, acc[3][0]); acc[3][1] = fmaf(av.w, wv.y, acc[3][1]);
            acc[3][2] = fmaf(av.w, wv.z, acc[3][2]); acc[3][3] = fmaf(av.w, wv.w, acc[3][3]);
        }
    }
#pragma unroll
    for (int i = 0; i < 4; i++) {
        int row = bm * 64 + ty * 4 + i;
        float* Crow = C + (size_t)row * N + bn * 64 + tx * 4;
        float4 o = make_float4(acc[i][0], acc[i][1], acc[i][2], acc[i][3]);
        if (ADD) {
            float4 c = *(const float4*)Crow;
            o.x += c.x; o.y += c.y; o.z += c.z; o.w += c.w;
        }
        *(float4*)Crow = o;
    }
}

// ---------- K4: causal depthwise conv (k=4) + bias + silu ----------
__global__ __launch_bounds__(256) void k_conv(const float* xz, const void* cw, const void* cb,
                                              int layer, float* u, const int* flag) {
    int bf = *flag;
    int idx = blockIdx.x * 256 + threadIdx.x;  // over ROWS*DI
    int d = idx & (DI - 1);
    int row = idx >> 9;
    int l = row & (SEQ - 1);
    float4 w = ldg4(cw, (layer * DI + d) * 4, bf);
    float acc = ldg1(cb, layer * DI + d, bf);
    const float* base = xz + (size_t)row * (2 * DI) + d;
    if (l >= 3) acc = fmaf(w.x, base[-3 * 2 * DI], acc);
    if (l >= 2) acc = fmaf(w.y, base[-2 * 2 * DI], acc);
    if (l >= 1) acc = fmaf(w.z, base[-1 * 2 * DI], acc);
    acc = fmaf(w.w, base[0], acc);
    float s = acc / (1.0f + __expf(-acc));  // silu
    u[(size_t)row * DI + d] = s;
}

// ---------- K5: x_proj GEMM  dbc[M,48] = u[M,512] @ W[48,512]^T ----------
__global__ __launch_bounds__(256) void k_xproj(const float* A, const void* W, int w_off,
                                               float* dbc, const int* flag) {
    int bf = *flag;
    __shared__ float As[16][68];
    __shared__ float Ws[16][52];
    int bm = blockIdx.x;
    int t = threadIdx.x;
    int lr = t >> 2, lk = (t & 3) * 4;
    const float* Arow = A + (size_t)(bm * 64 + lr) * DI + lk;
    int ty = t >> 4, tx = t & 15;
    float acc[4][3] = {};
    for (int k0 = 0; k0 < DI; k0 += 16) {
        float4 a = *(const float4*)(Arow + k0);
        float4 w = make_float4(0.f, 0.f, 0.f, 0.f);
        if (t < 192) w = ldg4(W, w_off + lr * DI + k0 + lk, bf);
        __syncthreads();
        As[lk + 0][lr] = a.x; As[lk + 1][lr] = a.y; As[lk + 2][lr] = a.z; As[lk + 3][lr] = a.w;
        if (t < 192) { Ws[lk + 0][lr] = w.x; Ws[lk + 1][lr] = w.y; Ws[lk + 2][lr] = w.z; Ws[lk + 3][lr] = w.w; }
        __syncthreads();
#pragma unroll
        for (int kk = 0; kk < 16; kk++) {
            float4 av = *(const float4*)&As[kk][ty * 4];
            float w0 = Ws[kk][tx * 3 + 0], w1 = Ws[kk][tx * 3 + 1], w2 = Ws[kk][tx * 3 + 2];
            acc[0][0] = fmaf(av.x, w0, acc[0][0]); acc[0][1] = fmaf(av.x, w1, acc[0][1]); acc[0][2] = fmaf(av.x, w2, acc[0][2]);
            acc[1][0] = fmaf(av.y, w0, acc[1][0]); acc[1][1] = fmaf(av.y, w1, acc[1][1]); acc[1][2] = fmaf(av.y, w2, acc[1][2]);
            acc[2][0] = fmaf(av.z, w0, acc[2][0]); acc[2][1] = fmaf(av.z, w1, acc[2][1]); acc[2][2] = fmaf(av.z, w2, acc[2][2]);
            acc[3][0] = fmaf(av.w, w0, acc[3][0]); acc[3][1] = fmaf(av.w, w1, acc[3][1]); acc[3][2] = fmaf(av.w, w2, acc[3][2]);
        }
    }
#pragma unroll
    for (int i = 0; i < 4; i++) {
        int row = bm * 64 + ty * 4 + i;
#pragma unroll
        for (int j = 0; j < 3; j++) dbc[(size_t)row * 48 + tx * 3 + j] = acc[i][j];
    }
}

// ---------- K6: dt projection + softplus ----------
__global__ __launch_bounds__(256) void k_dt(const float* dbc, const void* dtw, const void* dtb,
                                            int layer, float* delta, const int* flag) {
    int bf = *flag;
    int row = blockIdx.x;
    int t = threadIdx.x;
    __shared__ float s[16];
    if (t < 16) s[t] = dbc[(size_t)row * 48 + t];
    __syncthreads();
#pragma unroll
    for (int p = 0; p < 2; p++) {
        int d = t + p * 256;
        float acc = ldg1(dtb, layer * DI + d, bf);
#pragma unroll
        for (int kq = 0; kq < 4; kq++) {
            float4 w = ldg4(dtw, (layer * DI + d) * 16 + kq * 4, bf);
            acc = fmaf(s[kq * 4 + 0], w.x, acc);
            acc = fmaf(s[kq * 4 + 1], w.y, acc);
            acc = fmaf(s[kq * 4 + 2], w.z, acc);
            acc = fmaf(s[kq * 4 + 3], w.w, acc);
        }
        float sp = (acc > 20.0f) ? acc : log1pf(__expf(acc));  // softplus
        delta[(size_t)row * DI + d] = sp;
    }
}

// ---------- K7: selective scan + gating ----------
#define SCAN_T 64
__global__ __launch_bounds__(256) void k_scan(const float* delta, const float* u, const float* dbc,
                                              const void* A_log, const void* D_skip, const float* xz,
                                              float* g, int layer, const int* flag) {
    int bf = *flag;
    int blk = blockIdx.x;         // 256 blocks = 8 batches * 32 d-groups
    int b = blk >> 5, dg = blk & 31;
    int d0 = dg * 16;
    int t = threadIdx.x;
    int n = t & 15, dl = t >> 4;  // state index, channel-lane
    int d = d0 + dl;
    float Ad = -__expf(ldg1(A_log, (layer * DI + d) * DS + n, bf));
    float Dp = ldg1(D_skip, layer * DI + d, bf);
    __shared__ float sD[SCAN_T][16], sU[SCAN_T][16], sB[SCAN_T][16], sC[SCAN_T][16], sY[SCAN_T][16];
    float h = 0.0f;
    int r = t >> 2, q = (t & 3) * 4;     // staging map: 64 rows x 4 float4
    for (int t0 = 0; t0 < SEQ; t0 += SCAN_T) {
        size_t row = (size_t)b * SEQ + t0 + r;
        __syncthreads();
        *(float4*)&sD[r][q] = *(const float4*)(delta + row * DI + d0 + q);
        *(float4*)&sU[r][q] = *(const float4*)(u + row * DI + d0 + q);
        *(float4*)&sB[r][q] = *(const float4*)(dbc + row * 48 + DTR + q);
        *(float4*)&sC[r][q] = *(const float4*)(dbc + row * 48 + DTR + DS + q);
        __syncthreads();
#pragma unroll 4
        for (int tt = 0; tt < SCAN_T; tt++) {
            float dlt = sD[tt][dl];
            float uu  = sU[tt][dl];
            float dA  = __expf(dlt * Ad);
            float dBu = dlt * uu * sB[tt][n];
            h = fmaf(dA, h, dBu);
            float yp = sC[tt][n] * h;
            yp += __shfl_xor(yp, 1);
            yp += __shfl_xor(yp, 2);
            yp += __shfl_xor(yp, 4);
            yp += __shfl_xor(yp, 8);
            if (n == 0) sY[tt][dl] = yp + uu * Dp;
        }
        __syncthreads();
        // gating: g = y * silu(z); writes back over rows already consumed
        float4 y4 = *(float4*)&sY[r][q];
        float4 z4 = *(const float4*)(xz + row * (2 * DI) + DI + d0 + q);
        float4 g4;
        g4.x = y4.x * (z4.x / (1.0f + __expf(-z4.x)));
        g4.y = y4.y * (z4.y / (1.0f + __expf(-z4.y)));
        g4.z = y4.z * (z4.z / (1.0f + __expf(-z4.z)));
        g4.w = y4.w * (z4.w / (1.0f + __expf(-z4.w)));
        *(float4*)(g + row * DI + d0 + q) = g4;
    }
}

// ---------- K9: head ----------
__global__ __launch_bounds__(256) void k_head(const float* h, const void* w_head, const void* b_head,
                                              void* out, const int* flag) {
    int bf = *flag;
    int wv = threadIdx.x >> 6, ln = threadIdx.x & 63;
    int row = blockIdx.x * 4 + wv;
    float4 v = *(const float4*)(h + (size_t)row * DM + ln * 4);
    float4 w = ldg4(w_head, ln * 4, bf);
    float s = v.x * w.x + v.y * w.y + v.z * w.z + v.w * w.w;
    for (int o = 1; o < 64; o <<= 1) s += __shfl_xor(s, o);
    if (ln == 0) {
        s += ldg1(b_head, 0, bf);
        if (bf) ((__hip_bfloat16*)out)[row] = __float2bfloat16(s);
        else    ((float*)out)[row] = s;
    }
}

extern "C" void kernel_launch(void* const* d_in, const int* in_sizes, int n_in,
                              void* d_out, int out_size, void* d_ws, size_t ws_size,
                              hipStream_t stream) {
    (void)in_sizes; (void)n_in; (void)out_size; (void)ws_size;
    const void* x      = d_in[0];
    const void* w_in   = d_in[1];
    const void* b_in   = d_in[2];
    const void* norm_w = d_in[3];
    const void* ipw    = d_in[4];
    const void* cw     = d_in[5];
    const void* cb     = d_in[6];
    const void* xpw    = d_in[7];
    const void* dtw    = d_in[8];
    const void* dtb    = d_in[9];
    const void* A_log  = d_in[10];
    const void* D_skip = d_in[11];
    const void* opw    = d_in[12];
    const void* w_head = d_in[13];
    const void* b_head = d_in[14];

    float* ws    = (float*)d_ws;
    float* h     = ws;                  // 16384*256  = 4,194,304
    float* xn    = h + 4194304;         // 4,194,304
    float* xz    = xn + 4194304;        // 16384*1024 = 16,777,216
    float* u     = xz + 16777216;       // 16384*512  = 8,388,608
    float* dbc   = u + 8388608;         // 16384*48   = 786,432
    float* delta = dbc + 786432;        // 8,388,608
    int*   flag  = (int*)(delta + 8388608);

    k_probe<<<1, 64, 0, stream>>>(x, flag);
    k_inproj<<<ROWS, 256, 0, stream>>>(x, w_in, b_in, h, flag);

    for (int layer = 0; layer < NL; layer++) {
        k_rmsnorm<<<ROWS / 4, 256, 0, stream>>>(h, norm_w, layer * DM, xn, flag);
        k_gemm64<false><<<dim3(2 * DI / 64, ROWS / 64), 256, 0, stream>>>(
            xn, ipw, layer * 2 * DI * DM, xz, 2 * DI, DM, flag);
        k_conv<<<ROWS * DI / 256, 256, 0, stream>>>(xz, cw, cb, layer, u, flag);
        k_xproj<<<ROWS / 64, 256, 0, stream>>>(u, xpw, layer * 48 * DI, dbc, flag);
        k_dt<<<ROWS, 256, 0, stream>>>(dbc, dtw, dtb, layer, delta, flag);
        k_scan<<<256, 256, 0, stream>>>(delta, u, dbc, A_log, D_skip, xz, u /*g aliases u*/, layer, flag);
        k_gemm64<true><<<dim3(DM / 64, ROWS / 64), 256, 0, stream>>>(
            u, opw, layer * DM * DI, h, DM, DI, flag);
    }

    k_head<<<ROWS / 4, 256, 0, stream>>>(h, w_head, b_head, d_out, flag);
}

// Round 2
// 1618.794 us; speedup vs baseline: 1.8430x; 1.8430x over previous
//
#include <hip/hip_runtime.h>
#include <hip/hip_bf16.h>

#define BATCH 8
#define SEQ   2048
#define DM    256
#define DI    512
#define DS    16
#define DTR   16
#define NL    4
#define ROWS  (BATCH*SEQ)   // 16384
#define NCH   32            // chunks for the scan
#define CHL   64            // SEQ / NCH

// ---------- dtype-flexible load helpers ----------
__device__ __forceinline__ float bf2f(unsigned short u) {
    union { unsigned int i; float f; } v; v.i = ((unsigned int)u) << 16; return v.f;
}
__device__ __forceinline__ float ldg1(const void* p, int i, int bf) {
    if (bf) return bf2f(((const unsigned short*)p)[i]);
    return ((const float*)p)[i];
}
__device__ __forceinline__ float4 ldg4(const void* p, int i, int bf) { // i % 4 == 0
    if (bf) {
        ushort4 q = *(const ushort4*)(((const unsigned short*)p) + i);
        return make_float4(bf2f(q.x), bf2f(q.y), bf2f(q.z), bf2f(q.w));
    }
    return *(const float4*)(((const float*)p) + i);
}

// ---------- K0: dtype probe ----------
__global__ void k_probe(const void* x, int* flag) {
    int t = threadIdx.x;  // 64 threads
    float v = bf2f(((const unsigned short*)x)[2 * t]);
    int bad = (fabsf(v) < 32.0f) ? 0 : 1;  // NaN -> bad
    for (int o = 1; o < 64; o <<= 1) bad += __shfl_xor(bad, o);
    if (t == 0) *flag = (bad > 8) ? 0 : 1;  // 0 = f32, 1 = bf16
}

// ---------- K1: input projection  h = x @ w_in^T + b_in ----------
__global__ __launch_bounds__(256) void k_inproj(const void* x, const void* w_in,
                                                const void* b_in, float* h, const int* flag) {
    int bf = *flag;
    int row = blockIdx.x, e = threadIdx.x;
    float x0 = ldg1(x, row * 2 + 0, bf), x1 = ldg1(x, row * 2 + 1, bf);
    float w0 = ldg1(w_in, e * 2 + 0, bf), w1 = ldg1(w_in, e * 2 + 1, bf);
    float bb = ldg1(b_in, e, bf);
    h[(size_t)row * DM + e] = fmaf(x0, w0, fmaf(x1, w1, bb));
}

// ---------- K2: rmsnorm ----------
__global__ __launch_bounds__(256) void k_rmsnorm(const float* h, const void* norm_w,
                                                 int w_off, float* xn, const int* flag) {
    int bf = *flag;
    int wv = threadIdx.x >> 6, ln = threadIdx.x & 63;
    int row = blockIdx.x * 4 + wv;
    float4 v = *(const float4*)(h + (size_t)row * DM + ln * 4);
    float ss = v.x * v.x + v.y * v.y + v.z * v.z + v.w * v.w;
    for (int o = 1; o < 64; o <<= 1) ss += __shfl_xor(ss, o);
    float sc = rsqrtf(ss / DM + 1e-5f);
    float4 w = ldg4(norm_w, w_off + ln * 4, bf);
    float4 o;
    o.x = v.x * sc * w.x; o.y = v.y * sc * w.y; o.z = v.z * sc * w.z; o.w = v.w * sc * w.w;
    *(float4*)(xn + (size_t)row * DM + ln * 4) = o;
}

// ---------- K3/K8: tiled fp32 GEMM  C[M,N] (+)= A[M,K] @ W[N,K]^T ----------
template <bool ADD>
__global__ __launch_bounds__(256) void k_gemm64(const float* A, const void* W, int w_off,
                                                float* C, int N, int K, const int* flag) {
    int bf = *flag;
    __shared__ float As[16][68];
    __shared__ float Ws[16][68];
    int bn = blockIdx.x, bm = blockIdx.y;
    int t = threadIdx.x;
    int lr = t >> 2, lk = (t & 3) * 4;
    const float* Arow = A + (size_t)(bm * 64 + lr) * K + lk;
    int wbase = w_off + (bn * 64 + lr) * K + lk;
    int ty = t >> 4, tx = t & 15;
    float acc[4][4] = {};
    for (int k0 = 0; k0 < K; k0 += 16) {
        float4 a = *(const float4*)(Arow + k0);
        float4 w = ldg4(W, wbase + k0, bf);
        __syncthreads();
        As[lk + 0][lr] = a.x; As[lk + 1][lr] = a.y; As[lk + 2][lr] = a.z; As[lk + 3][lr] = a.w;
        Ws[lk + 0][lr] = w.x; Ws[lk + 1][lr] = w.y; Ws[lk + 2][lr] = w.z; Ws[lk + 3][lr] = w.w;
        __syncthreads();
#pragma unroll
        for (int kk = 0; kk < 16; kk++) {
            float4 av = *(const float4*)&As[kk][ty * 4];
            float4 wv = *(const float4*)&Ws[kk][tx * 4];
            acc[0][0] = fmaf(av.x, wv.x, acc[0][0]); acc[0][1] = fmaf(av.x, wv.y, acc[0][1]);
            acc[0][2] = fmaf(av.x, wv.z, acc[0][2]); acc[0][3] = fmaf(av.x, wv.w, acc[0][3]);
            acc[1][0] = fmaf(av.y, wv.x, acc[1][0]); acc[1][1] = fmaf(av.y, wv.y, acc[1][1]);
            acc[1][2] = fmaf(av.y, wv.z, acc[1][2]); acc[1][3] = fmaf(av.y, wv.w, acc[1][3]);
            acc[2][0] = fmaf(av.z, wv.x, acc[2][0]); acc[2][1] = fmaf(av.z, wv.y, acc[2][1]);
            acc[2][2] = fmaf(av.z, wv.z, acc[2][2]); acc[2][3] = fmaf(av.z, wv.w, acc[2][3]);
            acc[3][0] = fmaf(av.w, wv.x, acc[3][0]); acc[3][1] = fmaf(av.w, wv.y, acc[3][1]);
            acc[3][2] = fmaf(av.w, wv.z, acc[3][2]); acc[3][3] = fmaf(av.w, wv.w, acc[3][3]);
        }
    }
#pragma unroll
    for (int i = 0; i < 4; i++) {
        int row = bm * 64 + ty * 4 + i;
        float* Crow = C + (size_t)row * N + bn * 64 + tx * 4;
        float4 o = make_float4(acc[i][0], acc[i][1], acc[i][2], acc[i][3]);
        if (ADD) {
            float4 c = *(const float4*)Crow;
            o.x += c.x; o.y += c.y; o.z += c.z; o.w += c.w;
        }
        *(float4*)Crow = o;
    }
}

// ---------- K4: causal depthwise conv (k=4) + bias + silu ----------
__global__ __launch_bounds__(256) void k_conv(const float* xz, const void* cw, const void* cb,
                                              int layer, float* u, const int* flag) {
    int bf = *flag;
    int idx = blockIdx.x * 256 + threadIdx.x;  // over ROWS*DI
    int d = idx & (DI - 1);
    int row = idx >> 9;
    int l = row & (SEQ - 1);
    float4 w = ldg4(cw, (layer * DI + d) * 4, bf);
    float acc = ldg1(cb, layer * DI + d, bf);
    const float* base = xz + (size_t)row * (2 * DI) + d;
    if (l >= 3) acc = fmaf(w.x, base[-3 * 2 * DI], acc);
    if (l >= 2) acc = fmaf(w.y, base[-2 * 2 * DI], acc);
    if (l >= 1) acc = fmaf(w.z, base[-1 * 2 * DI], acc);
    acc = fmaf(w.w, base[0], acc);
    float s = acc / (1.0f + __expf(-acc));  // silu
    u[(size_t)row * DI + d] = s;
}

// ---------- K5: x_proj GEMM  dbc[M,48] = u[M,512] @ W[48,512]^T ----------
__global__ __launch_bounds__(256) void k_xproj(const float* A, const void* W, int w_off,
                                               float* dbc, const int* flag) {
    int bf = *flag;
    __shared__ float As[16][68];
    __shared__ float Ws[16][52];
    int bm = blockIdx.x;
    int t = threadIdx.x;
    int lr = t >> 2, lk = (t & 3) * 4;
    const float* Arow = A + (size_t)(bm * 64 + lr) * DI + lk;
    int ty = t >> 4, tx = t & 15;
    float acc[4][3] = {};
    for (int k0 = 0; k0 < DI; k0 += 16) {
        float4 a = *(const float4*)(Arow + k0);
        float4 w = make_float4(0.f, 0.f, 0.f, 0.f);
        if (t < 192) w = ldg4(W, w_off + lr * DI + k0 + lk, bf);
        __syncthreads();
        As[lk + 0][lr] = a.x; As[lk + 1][lr] = a.y; As[lk + 2][lr] = a.z; As[lk + 3][lr] = a.w;
        if (t < 192) { Ws[lk + 0][lr] = w.x; Ws[lk + 1][lr] = w.y; Ws[lk + 2][lr] = w.z; Ws[lk + 3][lr] = w.w; }
        __syncthreads();
#pragma unroll
        for (int kk = 0; kk < 16; kk++) {
            float4 av = *(const float4*)&As[kk][ty * 4];
            float w0 = Ws[kk][tx * 3 + 0], w1 = Ws[kk][tx * 3 + 1], w2 = Ws[kk][tx * 3 + 2];
            acc[0][0] = fmaf(av.x, w0, acc[0][0]); acc[0][1] = fmaf(av.x, w1, acc[0][1]); acc[0][2] = fmaf(av.x, w2, acc[0][2]);
            acc[1][0] = fmaf(av.y, w0, acc[1][0]); acc[1][1] = fmaf(av.y, w1, acc[1][1]); acc[1][2] = fmaf(av.y, w2, acc[1][2]);
            acc[2][0] = fmaf(av.z, w0, acc[2][0]); acc[2][1] = fmaf(av.z, w1, acc[2][1]); acc[2][2] = fmaf(av.z, w2, acc[2][2]);
            acc[3][0] = fmaf(av.w, w0, acc[3][0]); acc[3][1] = fmaf(av.w, w1, acc[3][1]); acc[3][2] = fmaf(av.w, w2, acc[3][2]);
        }
    }
#pragma unroll
    for (int i = 0; i < 4; i++) {
        int row = bm * 64 + ty * 4 + i;
#pragma unroll
        for (int j = 0; j < 3; j++) dbc[(size_t)row * 48 + tx * 3 + j] = acc[i][j];
    }
}

// ---------- K6: dt projection + softplus ----------
__global__ __launch_bounds__(256) void k_dt(const float* dbc, const void* dtw, const void* dtb,
                                            int layer, float* delta, const int* flag) {
    int bf = *flag;
    int row = blockIdx.x;
    int t = threadIdx.x;
    __shared__ float s[16];
    if (t < 16) s[t] = dbc[(size_t)row * 48 + t];
    __syncthreads();
#pragma unroll
    for (int p = 0; p < 2; p++) {
        int d = t + p * 256;
        float acc = ldg1(dtb, layer * DI + d, bf);
#pragma unroll
        for (int kq = 0; kq < 4; kq++) {
            float4 w = ldg4(dtw, (layer * DI + d) * 16 + kq * 4, bf);
            acc = fmaf(s[kq * 4 + 0], w.x, acc);
            acc = fmaf(s[kq * 4 + 1], w.y, acc);
            acc = fmaf(s[kq * 4 + 2], w.z, acc);
            acc = fmaf(s[kq * 4 + 3], w.w, acc);
        }
        float sp = (acc > 20.0f) ? acc : log1pf(__expf(acc));  // softplus
        delta[(size_t)row * DI + d] = sp;
    }
}

// ---------- K7a: scan pass 1 — per-chunk transition product P and zero-init endpoint E ----------
__global__ __launch_bounds__(256) void k_scan1(const float* delta, const float* u, const float* dbc,
                                               const void* A_log, float* P, float* E,
                                               int layer, const int* flag) {
    int bf = *flag;
    int x = blockIdx.x;                 // 512 = b(8) * c(32) * dg(2)
    int dg = x & 1, c = (x >> 1) & (NCH - 1), b = x >> 6;
    int tid = threadIdx.x;
    int d = dg * 256 + tid;
    int t0 = c * CHL;

    __shared__ float sB[CHL][16];
    {   // cooperative stage of B rows t0..t0+CHL-1 (16 floats each)
        int r = tid >> 2, q = tid & 3;
        *(float4*)&sB[r][q * 4] =
            *(const float4*)(dbc + ((size_t)b * SEQ + t0 + r) * 48 + DTR + q * 4);
    }

    float A[16];
#pragma unroll
    for (int n4 = 0; n4 < 4; n4++) {
        float4 a4 = ldg4(A_log, (layer * DI + d) * DS + n4 * 4, bf);
        A[n4 * 4 + 0] = -__expf(a4.x);
        A[n4 * 4 + 1] = -__expf(a4.y);
        A[n4 * 4 + 2] = -__expf(a4.z);
        A[n4 * 4 + 3] = -__expf(a4.w);
    }
    float h[16];
    float Pp[16];
#pragma unroll
    for (int n = 0; n < 16; n++) { h[n] = 0.0f; Pp[n] = 1.0f; }

    const float* dp = delta + ((size_t)b * SEQ + t0) * DI + d;
    const float* up = u + ((size_t)b * SEQ + t0) * DI + d;

    float dl0[4], uu0[4];
#pragma unroll
    for (int j = 0; j < 4; j++) { dl0[j] = dp[j * DI]; uu0[j] = up[j * DI]; }
    __syncthreads();

    for (int s = 0; s < CHL / 4; s++) {
        int sn = (s + 1 < CHL / 4) ? (s + 1) : s;     // clamped prefetch
        float dl1[4], uu1[4];
#pragma unroll
        for (int j = 0; j < 4; j++) {
            dl1[j] = dp[(sn * 4 + j) * DI];
            uu1[j] = up[(sn * 4 + j) * DI];
        }
#pragma unroll
        for (int j = 0; j < 4; j++) {
            int t = s * 4 + j;
            float dlt = dl0[j], uu = uu0[j];
            float du = dlt * uu;
#pragma unroll
            for (int n4 = 0; n4 < 4; n4++) {
                float4 Bv = *(const float4*)&sB[t][n4 * 4];
                int n = n4 * 4;
                float a0 = __expf(dlt * A[n + 0]); h[n + 0] = fmaf(a0, h[n + 0], du * Bv.x); Pp[n + 0] *= a0;
                float a1 = __expf(dlt * A[n + 1]); h[n + 1] = fmaf(a1, h[n + 1], du * Bv.y); Pp[n + 1] *= a1;
                float a2 = __expf(dlt * A[n + 2]); h[n + 2] = fmaf(a2, h[n + 2], du * Bv.z); Pp[n + 2] *= a2;
                float a3 = __expf(dlt * A[n + 3]); h[n + 3] = fmaf(a3, h[n + 3], du * Bv.w); Pp[n + 3] *= a3;
            }
        }
#pragma unroll
        for (int j = 0; j < 4; j++) { dl0[j] = dl1[j]; uu0[j] = uu1[j]; }
    }
    float* Pd = P + (((size_t)b * NCH + c) * DI + d) * DS;
    float* Ed = E + (((size_t)b * NCH + c) * DI + d) * DS;
#pragma unroll
    for (int n4 = 0; n4 < 4; n4++) {
        *(float4*)(Pd + n4 * 4) = make_float4(Pp[n4 * 4], Pp[n4 * 4 + 1], Pp[n4 * 4 + 2], Pp[n4 * 4 + 3]);
        *(float4*)(Ed + n4 * 4) = make_float4(h[n4 * 4], h[n4 * 4 + 1], h[n4 * 4 + 2], h[n4 * 4 + 3]);
    }
}

// ---------- K7b: stitch — sequential over chunks; rewrites E[c] with the state ENTERING chunk c ----------
__global__ __launch_bounds__(256) void k_stitch(float* P, float* E) {
    int g = blockIdx.x * 256 + threadIdx.x;   // 65536 threads over b(8) * d(512) * n(16)
    int b = g >> 13, r = g & 8191;
    size_t base = (size_t)b * NCH * (DI * DS) + r;
    float H = 0.0f;
#pragma unroll 4
    for (int c = 0; c < NCH; c++) {
        size_t idx = base + (size_t)c * (DI * DS);
        float p = P[idx], e = E[idx];
        E[idx] = H;                 // incoming state for chunk c
        H = fmaf(p, H, e);
    }
}

// ---------- K7c: scan pass 2 — full scan within chunk from correct h0, emit y*silu(z) ----------
__global__ __launch_bounds__(256) void k_scan2(const float* delta, const float* u, const float* dbc,
                                               const void* A_log, const void* D_skip, const float* xz,
                                               const float* E, float* g, int layer, const int* flag) {
    int bf = *flag;
    int x = blockIdx.x;
    int dg = x & 1, c = (x >> 1) & (NCH - 1), b = x >> 6;
    int tid = threadIdx.x;
    int d = dg * 256 + tid;
    int t0 = c * CHL;

    __shared__ float sBC[CHL][32];   // [t][0..15]=B, [16..31]=C
#pragma unroll
    for (int k2 = 0; k2 < 2; k2++) {
        int fi = k2 * 256 + tid;
        int r = fi >> 3, q = fi & 7;
        *(float4*)&sBC[r][q * 4] =
            *(const float4*)(dbc + ((size_t)b * SEQ + t0 + r) * 48 + DTR + q * 4);
    }

    float A[16];
#pragma unroll
    for (int n4 = 0; n4 < 4; n4++) {
        float4 a4 = ldg4(A_log, (layer * DI + d) * DS + n4 * 4, bf);
        A[n4 * 4 + 0] = -__expf(a4.x);
        A[n4 * 4 + 1] = -__expf(a4.y);
        A[n4 * 4 + 2] = -__expf(a4.z);
        A[n4 * 4 + 3] = -__expf(a4.w);
    }
    float Dp = ldg1(D_skip, layer * DI + d, bf);

    float h[16];
    const float* E0 = E + (((size_t)b * NCH + c) * DI + d) * DS;
#pragma unroll
    for (int n4 = 0; n4 < 4; n4++) {
        float4 h4 = *(const float4*)(E0 + n4 * 4);
        h[n4 * 4 + 0] = h4.x; h[n4 * 4 + 1] = h4.y; h[n4 * 4 + 2] = h4.z; h[n4 * 4 + 3] = h4.w;
    }

    const float* dp = delta + ((size_t)b * SEQ + t0) * DI + d;
    const float* up = u + ((size_t)b * SEQ + t0) * DI + d;
    const float* zp = xz + ((size_t)b * SEQ + t0) * (2 * DI) + DI + d;
    float* gp = g + ((size_t)b * SEQ + t0) * DI + d;

    float dl0[4], uu0[4], zz0[4];
#pragma unroll
    for (int j = 0; j < 4; j++) {
        dl0[j] = dp[j * DI]; uu0[j] = up[j * DI]; zz0[j] = zp[j * (2 * DI)];
    }
    __syncthreads();

    for (int s = 0; s < CHL / 4; s++) {
        int sn = (s + 1 < CHL / 4) ? (s + 1) : s;
        float dl1[4], uu1[4], zz1[4];
#pragma unroll
        for (int j = 0; j < 4; j++) {
            dl1[j] = dp[(sn * 4 + j) * DI];
            uu1[j] = up[(sn * 4 + j) * DI];
            zz1[j] = zp[(sn * 4 + j) * (2 * DI)];
        }
#pragma unroll
        for (int j = 0; j < 4; j++) {
            int t = s * 4 + j;
            float dlt = dl0[j], uu = uu0[j], zz = zz0[j];
            float du = dlt * uu;
            float y = 0.0f;
#pragma unroll
            for (int n4 = 0; n4 < 4; n4++) {
                float4 Bv = *(const float4*)&sBC[t][n4 * 4];
                float4 Cv = *(const float4*)&sBC[t][16 + n4 * 4];
                int n = n4 * 4;
                float a0 = __expf(dlt * A[n + 0]); h[n + 0] = fmaf(a0, h[n + 0], du * Bv.x); y = fmaf(Cv.x, h[n + 0], y);
                float a1 = __expf(dlt * A[n + 1]); h[n + 1] = fmaf(a1, h[n + 1], du * Bv.y); y = fmaf(Cv.y, h[n + 1], y);
                float a2 = __expf(dlt * A[n + 2]); h[n + 2] = fmaf(a2, h[n + 2], du * Bv.z); y = fmaf(Cv.z, h[n + 2], y);
                float a3 = __expf(dlt * A[n + 3]); h[n + 3] = fmaf(a3, h[n + 3], du * Bv.w); y = fmaf(Cv.w, h[n + 3], y);
            }
            float yt = fmaf(uu, Dp, y);
            float sg = zz / (1.0f + __expf(-zz));
            gp[(size_t)t * DI] = yt * sg;
        }
#pragma unroll
        for (int j = 0; j < 4; j++) { dl0[j] = dl1[j]; uu0[j] = uu1[j]; zz0[j] = zz1[j]; }
    }
}

// ---------- K9: head ----------
__global__ __launch_bounds__(256) void k_head(const float* h, const void* w_head, const void* b_head,
                                              void* out, const int* flag) {
    int bf = *flag;
    int wv = threadIdx.x >> 6, ln = threadIdx.x & 63;
    int row = blockIdx.x * 4 + wv;
    float4 v = *(const float4*)(h + (size_t)row * DM + ln * 4);
    float4 w = ldg4(w_head, ln * 4, bf);
    float s = v.x * w.x + v.y * w.y + v.z * w.z + v.w * w.w;
    for (int o = 1; o < 64; o <<= 1) s += __shfl_xor(s, o);
    if (ln == 0) {
        s += ldg1(b_head, 0, bf);
        if (bf) ((__hip_bfloat16*)out)[row] = __float2bfloat16(s);
        else    ((float*)out)[row] = s;
    }
}

extern "C" void kernel_launch(void* const* d_in, const int* in_sizes, int n_in,
                              void* d_out, int out_size, void* d_ws, size_t ws_size,
                              hipStream_t stream) {
    (void)in_sizes; (void)n_in; (void)out_size; (void)ws_size;
    const void* x      = d_in[0];
    const void* w_in   = d_in[1];
    const void* b_in   = d_in[2];
    const void* norm_w = d_in[3];
    const void* ipw    = d_in[4];
    const void* cw     = d_in[5];
    const void* cb     = d_in[6];
    const void* xpw    = d_in[7];
    const void* dtw    = d_in[8];
    const void* dtb    = d_in[9];
    const void* A_log  = d_in[10];
    const void* D_skip = d_in[11];
    const void* opw    = d_in[12];
    const void* w_head = d_in[13];
    const void* b_head = d_in[14];

    float* ws    = (float*)d_ws;
    float* h     = ws;                  // 4,194,304 floats
    float* xn    = h + 4194304;         // 4,194,304  (dead during scan -> P/E alias here)
    float* xz    = xn + 4194304;        // 16,777,216
    float* u     = xz + 16777216;       // 8,388,608
    float* dbc   = u + 8388608;         // 786,432
    float* delta = dbc + 786432;        // 8,388,608
    int*   flag  = (int*)(delta + 8388608);

    float* P = xn;                      // 8*32*512*16 = 2,097,152
    float* E = xn + 2097152;            // 2,097,152  -> exactly fills xn

    k_probe<<<1, 64, 0, stream>>>(x, flag);
    k_inproj<<<ROWS, 256, 0, stream>>>(x, w_in, b_in, h, flag);

    for (int layer = 0; layer < NL; layer++) {
        k_rmsnorm<<<ROWS / 4, 256, 0, stream>>>(h, norm_w, layer * DM, xn, flag);
        k_gemm64<false><<<dim3(2 * DI / 64, ROWS / 64), 256, 0, stream>>>(
            xn, ipw, layer * 2 * DI * DM, xz, 2 * DI, DM, flag);
        k_conv<<<ROWS * DI / 256, 256, 0, stream>>>(xz, cw, cb, layer, u, flag);
        k_xproj<<<ROWS / 64, 256, 0, stream>>>(u, xpw, layer * 48 * DI, dbc, flag);
        k_dt<<<ROWS, 256, 0, stream>>>(dbc, dtw, dtb, layer, delta, flag);
        k_scan1<<<BATCH * NCH * 2, 256, 0, stream>>>(delta, u, dbc, A_log, P, E, layer, flag);
        k_stitch<<<BATCH * DI * DS / 256, 256, 0, stream>>>(P, E);
        k_scan2<<<BATCH * NCH * 2, 256, 0, stream>>>(delta, u, dbc, A_log, D_skip, xz, E,
                                                     u /*g aliases u*/, layer, flag);
        k_gemm64<true><<<dim3(DM / 64, ROWS / 64), 256, 0, stream>>>(
            u, opw, layer * DM * DI, h, DM, DI, flag);
    }

    k_head<<<ROWS / 4, 256, 0, stream>>>(h, w_head, b_head, d_out, flag);
}

// Round 3
// 1169.562 us; speedup vs baseline: 2.5508x; 1.3841x over previous
//
#include <hip/hip_runtime.h>
#include <hip/hip_bf16.h>

#define BATCH 8
#define SEQ   2048
#define DM    256
#define DI    512
#define DS    16
#define DTR   16
#define NL    4
#define ROWS  (BATCH*SEQ)   // 16384
#define NCH   32            // chunks for the scan
#define CHL   64            // SEQ / NCH

typedef __attribute__((ext_vector_type(8))) __bf16 bh8;
typedef __attribute__((ext_vector_type(4))) float f4;

// ---------- dtype-flexible load helpers ----------
__device__ __forceinline__ float bf2f(unsigned short u) {
    union { unsigned int i; float f; } v; v.i = ((unsigned int)u) << 16; return v.f;
}
__device__ __forceinline__ float ldg1(const void* p, int i, int bf) {
    if (bf) return bf2f(((const unsigned short*)p)[i]);
    return ((const float*)p)[i];
}
__device__ __forceinline__ float4 ldg4(const void* p, int i, int bf) { // i % 4 == 0
    if (bf) {
        ushort4 q = *(const ushort4*)(((const unsigned short*)p) + i);
        return make_float4(bf2f(q.x), bf2f(q.y), bf2f(q.z), bf2f(q.w));
    }
    return *(const float4*)(((const float*)p) + i);
}
// f32 -> bf16 bits, round-to-nearest-even
__device__ __forceinline__ unsigned short f2bs(float f) {
    union { float f; unsigned u; } x; x.f = f;
    unsigned r = (x.u + 0x7fffu + ((x.u >> 16) & 1u)) >> 16;
    return (unsigned short)r;
}

// ---------- K0: dtype probe ----------
__global__ void k_probe(const void* x, int* flag) {
    int t = threadIdx.x;  // 64 threads
    float v = bf2f(((const unsigned short*)x)[2 * t]);
    int bad = (fabsf(v) < 32.0f) ? 0 : 1;  // NaN -> bad
    for (int o = 1; o < 64; o <<= 1) bad += __shfl_xor(bad, o);
    if (t == 0) *flag = (bad > 8) ? 0 : 1;  // 0 = f32, 1 = bf16
}

// ---------- K1: input projection  h = x @ w_in^T + b_in ----------
__global__ __launch_bounds__(256) void k_inproj(const void* x, const void* w_in,
                                                const void* b_in, float* h, const int* flag) {
    int bf = *flag;
    int row = blockIdx.x, e = threadIdx.x;
    float x0 = ldg1(x, row * 2 + 0, bf), x1 = ldg1(x, row * 2 + 1, bf);
    float w0 = ldg1(w_in, e * 2 + 0, bf), w1 = ldg1(w_in, e * 2 + 1, bf);
    float bb = ldg1(b_in, e, bf);
    h[(size_t)row * DM + e] = fmaf(x0, w0, fmaf(x1, w1, bb));
}

// ---------- K2: rmsnorm ----------
__global__ __launch_bounds__(256) void k_rmsnorm(const float* h, const void* norm_w,
                                                 int w_off, float* xn, const int* flag) {
    int bf = *flag;
    int wv = threadIdx.x >> 6, ln = threadIdx.x & 63;
    int row = blockIdx.x * 4 + wv;
    float4 v = *(const float4*)(h + (size_t)row * DM + ln * 4);
    float ss = v.x * v.x + v.y * v.y + v.z * v.z + v.w * v.w;
    for (int o = 1; o < 64; o <<= 1) ss += __shfl_xor(ss, o);
    float sc = rsqrtf(ss / DM + 1e-5f);
    float4 w = ldg4(norm_w, w_off + ln * 4, bf);
    float4 o;
    o.x = v.x * sc * w.x; o.y = v.y * sc * w.y; o.z = v.z * sc * w.z; o.w = v.w * sc * w.w;
    *(float4*)(xn + (size_t)row * DM + ln * 4) = o;
}

// ---------- K3: bf16 MFMA GEMM  C[M,N] (+)= A[M,K] @ W[N,K]^T ----------
// BM=128 fixed, BK=64, 4 waves in 2x2; wave computes 64 x (BN/2).
#define ASTR 72   // LDS row stride (ushorts): 64 + 8 pad -> 4-bank shift per row
template <int BN, bool ADD>
__global__ __launch_bounds__(256, 2) void k_mfma(const float* A, const void* W, int w_off,
                                                 float* C, int N, int K, const int* flag) {
    int bf = *flag;
    __shared__ unsigned short As[128 * ASTR];
    __shared__ unsigned short Ws[BN * ASTR];
    constexpr int NT = BN / 32;         // col-tiles per wave
    constexpr int WCH = BN * 8 / 256;   // W staging chunks per thread

    int bn = blockIdx.x, bm = blockIdx.y;
    int t = threadIdx.x;
    int w = t >> 6, lane = t & 63;
    int wm = w >> 1, wn = w & 1;
    int lr = lane & 15, quad = lane >> 4;

    f4 acc[4][NT];
#pragma unroll
    for (int i = 0; i < 4; i++)
#pragma unroll
        for (int j = 0; j < NT; j++) acc[i][j] = f4{0.f, 0.f, 0.f, 0.f};

    for (int k0 = 0; k0 < K; k0 += 64) {
        __syncthreads();
        // stage A (f32 -> bf16)
#pragma unroll
        for (int i = 0; i < 4; i++) {
            int ch = t + i * 256;
            int r = ch >> 3, kc = (ch & 7) * 8;
            const float* src = A + (size_t)(bm * 128 + r) * K + k0 + kc;
            float4 a0 = *(const float4*)src;
            float4 a1 = *(const float4*)(src + 4);
            ushort4 v0 = { f2bs(a0.x), f2bs(a0.y), f2bs(a0.z), f2bs(a0.w) };
            ushort4 v1 = { f2bs(a1.x), f2bs(a1.y), f2bs(a1.z), f2bs(a1.w) };
            *(ushort4*)&As[r * ASTR + kc] = v0;
            *(ushort4*)&As[r * ASTR + kc + 4] = v1;
        }
        // stage W (flag-aware)
#pragma unroll
        for (int i = 0; i < WCH; i++) {
            int ch = t + i * 256;
            int r = ch >> 3, kc = (ch & 7) * 8;
            size_t off = (size_t)w_off + (size_t)(bn * BN + r) * K + k0 + kc;
            if (bf) {
                *(uint4*)&Ws[r * ASTR + kc] = *(const uint4*)((const unsigned short*)W + off);
            } else {
                const float* src = (const float*)W + off;
                float4 a0 = *(const float4*)src;
                float4 a1 = *(const float4*)(src + 4);
                ushort4 v0 = { f2bs(a0.x), f2bs(a0.y), f2bs(a0.z), f2bs(a0.w) };
                ushort4 v1 = { f2bs(a1.x), f2bs(a1.y), f2bs(a1.z), f2bs(a1.w) };
                *(ushort4*)&Ws[r * ASTR + kc] = v0;
                *(ushort4*)&Ws[r * ASTR + kc + 4] = v1;
            }
        }
        __syncthreads();
#pragma unroll
        for (int ks = 0; ks < 64; ks += 32) {
            bh8 af[4];
#pragma unroll
            for (int i = 0; i < 4; i++)
                af[i] = *(const bh8*)&As[(wm * 64 + i * 16 + lr) * ASTR + ks + quad * 8];
            bh8 wf[NT];
#pragma unroll
            for (int j = 0; j < NT; j++)
                wf[j] = *(const bh8*)&Ws[(wn * (BN / 2) + j * 16 + lr) * ASTR + ks + quad * 8];
#pragma unroll
            for (int i = 0; i < 4; i++)
#pragma unroll
                for (int j = 0; j < NT; j++)
                    acc[i][j] = __builtin_amdgcn_mfma_f32_16x16x32_bf16(af[i], wf[j], acc[i][j], 0, 0, 0);
        }
    }
    // epilogue: C/D layout col=lane&15, row=quad*4+reg
#pragma unroll
    for (int i = 0; i < 4; i++) {
        int row0 = bm * 128 + wm * 64 + i * 16 + quad * 4;
#pragma unroll
        for (int j = 0; j < NT; j++) {
            int col = bn * BN + wn * (BN / 2) + j * 16 + lr;
#pragma unroll
            for (int r = 0; r < 4; r++) {
                size_t idx = (size_t)(row0 + r) * N + col;
                float v = acc[i][j][r];
                if (ADD) v += C[idx];
                C[idx] = v;
            }
        }
    }
}

// ---------- K4: causal depthwise conv (k=4) + bias + silu ----------
__global__ __launch_bounds__(256) void k_conv(const float* xz, const void* cw, const void* cb,
                                              int layer, float* u, const int* flag) {
    int bf = *flag;
    int idx = blockIdx.x * 256 + threadIdx.x;  // over ROWS*DI
    int d = idx & (DI - 1);
    int row = idx >> 9;
    int l = row & (SEQ - 1);
    float4 w = ldg4(cw, (layer * DI + d) * 4, bf);
    float acc = ldg1(cb, layer * DI + d, bf);
    const float* base = xz + (size_t)row * (2 * DI) + d;
    if (l >= 3) acc = fmaf(w.x, base[-3 * 2 * DI], acc);
    if (l >= 2) acc = fmaf(w.y, base[-2 * 2 * DI], acc);
    if (l >= 1) acc = fmaf(w.z, base[-1 * 2 * DI], acc);
    acc = fmaf(w.w, base[0], acc);
    float s = acc / (1.0f + __expf(-acc));  // silu
    u[(size_t)row * DI + d] = s;
}

// ---------- K5: x_proj GEMM  dbc[M,48] = u[M,512] @ W[48,512]^T ----------
__global__ __launch_bounds__(256) void k_xproj(const float* A, const void* W, int w_off,
                                               float* dbc, const int* flag) {
    int bf = *flag;
    __shared__ float As[16][68];
    __shared__ float Ws[16][52];
    int bm = blockIdx.x;
    int t = threadIdx.x;
    int lr = t >> 2, lk = (t & 3) * 4;
    const float* Arow = A + (size_t)(bm * 64 + lr) * DI + lk;
    int ty = t >> 4, tx = t & 15;
    float acc[4][3] = {};
    for (int k0 = 0; k0 < DI; k0 += 16) {
        float4 a = *(const float4*)(Arow + k0);
        float4 w = make_float4(0.f, 0.f, 0.f, 0.f);
        if (t < 192) w = ldg4(W, w_off + lr * DI + k0 + lk, bf);
        __syncthreads();
        As[lk + 0][lr] = a.x; As[lk + 1][lr] = a.y; As[lk + 2][lr] = a.z; As[lk + 3][lr] = a.w;
        if (t < 192) { Ws[lk + 0][lr] = w.x; Ws[lk + 1][lr] = w.y; Ws[lk + 2][lr] = w.z; Ws[lk + 3][lr] = w.w; }
        __syncthreads();
#pragma unroll
        for (int kk = 0; kk < 16; kk++) {
            float4 av = *(const float4*)&As[kk][ty * 4];
            float w0 = Ws[kk][tx * 3 + 0], w1 = Ws[kk][tx * 3 + 1], w2 = Ws[kk][tx * 3 + 2];
            acc[0][0] = fmaf(av.x, w0, acc[0][0]); acc[0][1] = fmaf(av.x, w1, acc[0][1]); acc[0][2] = fmaf(av.x, w2, acc[0][2]);
            acc[1][0] = fmaf(av.y, w0, acc[1][0]); acc[1][1] = fmaf(av.y, w1, acc[1][1]); acc[1][2] = fmaf(av.y, w2, acc[1][2]);
            acc[2][0] = fmaf(av.z, w0, acc[2][0]); acc[2][1] = fmaf(av.z, w1, acc[2][1]); acc[2][2] = fmaf(av.z, w2, acc[2][2]);
            acc[3][0] = fmaf(av.w, w0, acc[3][0]); acc[3][1] = fmaf(av.w, w1, acc[3][1]); acc[3][2] = fmaf(av.w, w2, acc[3][2]);
        }
    }
#pragma unroll
    for (int i = 0; i < 4; i++) {
        int row = bm * 64 + ty * 4 + i;
#pragma unroll
        for (int j = 0; j < 3; j++) dbc[(size_t)row * 48 + tx * 3 + j] = acc[i][j];
    }
}

// ---------- K6: dt projection + softplus ----------
__global__ __launch_bounds__(256) void k_dt(const float* dbc, const void* dtw, const void* dtb,
                                            int layer, float* delta, const int* flag) {
    int bf = *flag;
    int row = blockIdx.x;
    int t = threadIdx.x;
    __shared__ float s[16];
    if (t < 16) s[t] = dbc[(size_t)row * 48 + t];
    __syncthreads();
#pragma unroll
    for (int p = 0; p < 2; p++) {
        int d = t + p * 256;
        float acc = ldg1(dtb, layer * DI + d, bf);
#pragma unroll
        for (int kq = 0; kq < 4; kq++) {
            float4 w = ldg4(dtw, (layer * DI + d) * 16 + kq * 4, bf);
            acc = fmaf(s[kq * 4 + 0], w.x, acc);
            acc = fmaf(s[kq * 4 + 1], w.y, acc);
            acc = fmaf(s[kq * 4 + 2], w.z, acc);
            acc = fmaf(s[kq * 4 + 3], w.w, acc);
        }
        float sp = (acc > 20.0f) ? acc : log1pf(__expf(acc));  // softplus
        delta[(size_t)row * DI + d] = sp;
    }
}

// ---------- K7a: scan pass 1 — per-chunk transition product P and zero-init endpoint E ----------
__global__ __launch_bounds__(256) void k_scan1(const float* delta, const float* u, const float* dbc,
                                               const void* A_log, float* P, float* E,
                                               int layer, const int* flag) {
    int bf = *flag;
    int x = blockIdx.x;                 // 512 = b(8) * c(32) * dg(2)
    int dg = x & 1, c = (x >> 1) & (NCH - 1), b = x >> 6;
    int tid = threadIdx.x;
    int d = dg * 256 + tid;
    int t0 = c * CHL;

    __shared__ float sB[CHL][16];
    {   // cooperative stage of B rows t0..t0+CHL-1 (16 floats each)
        int r = tid >> 2, q = tid & 3;
        *(float4*)&sB[r][q * 4] =
            *(const float4*)(dbc + ((size_t)b * SEQ + t0 + r) * 48 + DTR + q * 4);
    }

    float A[16];
#pragma unroll
    for (int n4 = 0; n4 < 4; n4++) {
        float4 a4 = ldg4(A_log, (layer * DI + d) * DS + n4 * 4, bf);
        A[n4 * 4 + 0] = -__expf(a4.x);
        A[n4 * 4 + 1] = -__expf(a4.y);
        A[n4 * 4 + 2] = -__expf(a4.z);
        A[n4 * 4 + 3] = -__expf(a4.w);
    }
    float h[16];
    float Pp[16];
#pragma unroll
    for (int n = 0; n < 16; n++) { h[n] = 0.0f; Pp[n] = 1.0f; }

    const float* dp = delta + ((size_t)b * SEQ + t0) * DI + d;
    const float* up = u + ((size_t)b * SEQ + t0) * DI + d;

    float dl0[4], uu0[4];
#pragma unroll
    for (int j = 0; j < 4; j++) { dl0[j] = dp[j * DI]; uu0[j] = up[j * DI]; }
    __syncthreads();

    for (int s = 0; s < CHL / 4; s++) {
        int sn = (s + 1 < CHL / 4) ? (s + 1) : s;     // clamped prefetch
        float dl1[4], uu1[4];
#pragma unroll
        for (int j = 0; j < 4; j++) {
            dl1[j] = dp[(sn * 4 + j) * DI];
            uu1[j] = up[(sn * 4 + j) * DI];
        }
#pragma unroll
        for (int j = 0; j < 4; j++) {
            int t = s * 4 + j;
            float dlt = dl0[j], uu = uu0[j];
            float du = dlt * uu;
#pragma unroll
            for (int n4 = 0; n4 < 4; n4++) {
                float4 Bv = *(const float4*)&sB[t][n4 * 4];
                int n = n4 * 4;
                float a0 = __expf(dlt * A[n + 0]); h[n + 0] = fmaf(a0, h[n + 0], du * Bv.x); Pp[n + 0] *= a0;
                float a1 = __expf(dlt * A[n + 1]); h[n + 1] = fmaf(a1, h[n + 1], du * Bv.y); Pp[n + 1] *= a1;
                float a2 = __expf(dlt * A[n + 2]); h[n + 2] = fmaf(a2, h[n + 2], du * Bv.z); Pp[n + 2] *= a2;
                float a3 = __expf(dlt * A[n + 3]); h[n + 3] = fmaf(a3, h[n + 3], du * Bv.w); Pp[n + 3] *= a3;
            }
        }
#pragma unroll
        for (int j = 0; j < 4; j++) { dl0[j] = dl1[j]; uu0[j] = uu1[j]; }
    }
    float* Pd = P + (((size_t)b * NCH + c) * DI + d) * DS;
    float* Ed = E + (((size_t)b * NCH + c) * DI + d) * DS;
#pragma unroll
    for (int n4 = 0; n4 < 4; n4++) {
        *(float4*)(Pd + n4 * 4) = make_float4(Pp[n4 * 4], Pp[n4 * 4 + 1], Pp[n4 * 4 + 2], Pp[n4 * 4 + 3]);
        *(float4*)(Ed + n4 * 4) = make_float4(h[n4 * 4], h[n4 * 4 + 1], h[n4 * 4 + 2], h[n4 * 4 + 3]);
    }
}

// ---------- K7b: stitch — sequential over chunks; rewrites E[c] with the state ENTERING chunk c ----------
__global__ __launch_bounds__(256) void k_stitch(float* P, float* E) {
    int g = blockIdx.x * 256 + threadIdx.x;   // 65536 threads over b(8) * d(512) * n(16)
    int b = g >> 13, r = g & 8191;
    size_t base = (size_t)b * NCH * (DI * DS) + r;
    float H = 0.0f;
#pragma unroll 4
    for (int c = 0; c < NCH; c++) {
        size_t idx = base + (size_t)c * (DI * DS);
        float p = P[idx], e = E[idx];
        E[idx] = H;                 // incoming state for chunk c
        H = fmaf(p, H, e);
    }
}

// ---------- K7c: scan pass 2 — full scan within chunk from correct h0, emit y*silu(z) ----------
__global__ __launch_bounds__(256) void k_scan2(const float* delta, const float* u, const float* dbc,
                                               const void* A_log, const void* D_skip, const float* xz,
                                               const float* E, float* g, int layer, const int* flag) {
    int bf = *flag;
    int x = blockIdx.x;
    int dg = x & 1, c = (x >> 1) & (NCH - 1), b = x >> 6;
    int tid = threadIdx.x;
    int d = dg * 256 + tid;
    int t0 = c * CHL;

    __shared__ float sBC[CHL][32];   // [t][0..15]=B, [16..31]=C
#pragma unroll
    for (int k2 = 0; k2 < 2; k2++) {
        int fi = k2 * 256 + tid;
        int r = fi >> 3, q = fi & 7;
        *(float4*)&sBC[r][q * 4] =
            *(const float4*)(dbc + ((size_t)b * SEQ + t0 + r) * 48 + DTR + q * 4);
    }

    float A[16];
#pragma unroll
    for (int n4 = 0; n4 < 4; n4++) {
        float4 a4 = ldg4(A_log, (layer * DI + d) * DS + n4 * 4, bf);
        A[n4 * 4 + 0] = -__expf(a4.x);
        A[n4 * 4 + 1] = -__expf(a4.y);
        A[n4 * 4 + 2] = -__expf(a4.z);
        A[n4 * 4 + 3] = -__expf(a4.w);
    }
    float Dp = ldg1(D_skip, layer * DI + d, bf);

    float h[16];
    const float* E0 = E + (((size_t)b * NCH + c) * DI + d) * DS;
#pragma unroll
    for (int n4 = 0; n4 < 4; n4++) {
        float4 h4 = *(const float4*)(E0 + n4 * 4);
        h[n4 * 4 + 0] = h4.x; h[n4 * 4 + 1] = h4.y; h[n4 * 4 + 2] = h4.z; h[n4 * 4 + 3] = h4.w;
    }

    const float* dp = delta + ((size_t)b * SEQ + t0) * DI + d;
    const float* up = u + ((size_t)b * SEQ + t0) * DI + d;
    const float* zp = xz + ((size_t)b * SEQ + t0) * (2 * DI) + DI + d;
    float* gp = g + ((size_t)b * SEQ + t0) * DI + d;

    float dl0[4], uu0[4], zz0[4];
#pragma unroll
    for (int j = 0; j < 4; j++) {
        dl0[j] = dp[j * DI]; uu0[j] = up[j * DI]; zz0[j] = zp[j * (2 * DI)];
    }
    __syncthreads();

    for (int s = 0; s < CHL / 4; s++) {
        int sn = (s + 1 < CHL / 4) ? (s + 1) : s;
        float dl1[4], uu1[4], zz1[4];
#pragma unroll
        for (int j = 0; j < 4; j++) {
            dl1[j] = dp[(sn * 4 + j) * DI];
            uu1[j] = up[(sn * 4 + j) * DI];
            zz1[j] = zp[(sn * 4 + j) * (2 * DI)];
        }
#pragma unroll
        for (int j = 0; j < 4; j++) {
            int t = s * 4 + j;
            float dlt = dl0[j], uu = uu0[j], zz = zz0[j];
            float du = dlt * uu;
            float y = 0.0f;
#pragma unroll
            for (int n4 = 0; n4 < 4; n4++) {
                float4 Bv = *(const float4*)&sBC[t][n4 * 4];
                float4 Cv = *(const float4*)&sBC[t][16 + n4 * 4];
                int n = n4 * 4;
                float a0 = __expf(dlt * A[n + 0]); h[n + 0] = fmaf(a0, h[n + 0], du * Bv.x); y = fmaf(Cv.x, h[n + 0], y);
                float a1 = __expf(dlt * A[n + 1]); h[n + 1] = fmaf(a1, h[n + 1], du * Bv.y); y = fmaf(Cv.y, h[n + 1], y);
                float a2 = __expf(dlt * A[n + 2]); h[n + 2] = fmaf(a2, h[n + 2], du * Bv.z); y = fmaf(Cv.z, h[n + 2], y);
                float a3 = __expf(dlt * A[n + 3]); h[n + 3] = fmaf(a3, h[n + 3], du * Bv.w); y = fmaf(Cv.w, h[n + 3], y);
            }
            float yt = fmaf(uu, Dp, y);
            float sg = zz / (1.0f + __expf(-zz));
            gp[(size_t)t * DI] = yt * sg;
        }
#pragma unroll
        for (int j = 0; j < 4; j++) { dl0[j] = dl1[j]; uu0[j] = uu1[j]; zz0[j] = zz1[j]; }
    }
}

// ---------- K9: head ----------
__global__ __launch_bounds__(256) void k_head(const float* h, const void* w_head, const void* b_head,
                                              void* out, const int* flag) {
    int bf = *flag;
    int wv = threadIdx.x >> 6, ln = threadIdx.x & 63;
    int row = blockIdx.x * 4 + wv;
    float4 v = *(const float4*)(h + (size_t)row * DM + ln * 4);
    float4 w = ldg4(w_head, ln * 4, bf);
    float s = v.x * w.x + v.y * w.y + v.z * w.z + v.w * w.w;
    for (int o = 1; o < 64; o <<= 1) s += __shfl_xor(s, o);
    if (ln == 0) {
        s += ldg1(b_head, 0, bf);
        if (bf) ((__hip_bfloat16*)out)[row] = __float2bfloat16(s);
        else    ((float*)out)[row] = s;
    }
}

extern "C" void kernel_launch(void* const* d_in, const int* in_sizes, int n_in,
                              void* d_out, int out_size, void* d_ws, size_t ws_size,
                              hipStream_t stream) {
    (void)in_sizes; (void)n_in; (void)out_size; (void)ws_size;
    const void* x      = d_in[0];
    const void* w_in   = d_in[1];
    const void* b_in   = d_in[2];
    const void* norm_w = d_in[3];
    const void* ipw    = d_in[4];
    const void* cw     = d_in[5];
    const void* cb     = d_in[6];
    const void* xpw    = d_in[7];
    const void* dtw    = d_in[8];
    const void* dtb    = d_in[9];
    const void* A_log  = d_in[10];
    const void* D_skip = d_in[11];
    const void* opw    = d_in[12];
    const void* w_head = d_in[13];
    const void* b_head = d_in[14];

    float* ws    = (float*)d_ws;
    float* h     = ws;                  // 4,194,304 floats
    float* xn    = h + 4194304;         // 4,194,304  (dead during scan -> P/E alias here)
    float* xz    = xn + 4194304;        // 16,777,216
    float* u     = xz + 16777216;       // 8,388,608
    float* dbc   = u + 8388608;         // 786,432
    float* delta = dbc + 786432;        // 8,388,608
    int*   flag  = (int*)(delta + 8388608);

    float* P = xn;                      // 8*32*512*16 = 2,097,152
    float* E = xn + 2097152;            // 2,097,152  -> exactly fills xn

    k_probe<<<1, 64, 0, stream>>>(x, flag);
    k_inproj<<<ROWS, 256, 0, stream>>>(x, w_in, b_in, h, flag);

    for (int layer = 0; layer < NL; layer++) {
        k_rmsnorm<<<ROWS / 4, 256, 0, stream>>>(h, norm_w, layer * DM, xn, flag);
        k_mfma<128, false><<<dim3(2 * DI / 128, ROWS / 128), 256, 0, stream>>>(
            xn, ipw, layer * 2 * DI * DM, xz, 2 * DI, DM, flag);
        k_conv<<<ROWS * DI / 256, 256, 0, stream>>>(xz, cw, cb, layer, u, flag);
        k_xproj<<<ROWS / 64, 256, 0, stream>>>(u, xpw, layer * 48 * DI, dbc, flag);
        k_dt<<<ROWS, 256, 0, stream>>>(dbc, dtw, dtb, layer, delta, flag);
        k_scan1<<<BATCH * NCH * 2, 256, 0, stream>>>(delta, u, dbc, A_log, P, E, layer, flag);
        k_stitch<<<BATCH * DI * DS / 256, 256, 0, stream>>>(P, E);
        k_scan2<<<BATCH * NCH * 2, 256, 0, stream>>>(delta, u, dbc, A_log, D_skip, xz, E,
                                                     u /*g aliases u*/, layer, flag);
        k_mfma<64, true><<<dim3(DM / 64, ROWS / 128), 256, 0, stream>>>(
            u, opw, layer * DM * DI, h, DM, DI, flag);
    }

    k_head<<<ROWS / 4, 256, 0, stream>>>(h, w_head, b_head, d_out, flag);
}

// Round 4
// 1036.821 us; speedup vs baseline: 2.8774x; 1.1280x over previous
//
#include <hip/hip_runtime.h>
#include <hip/hip_bf16.h>

#define BATCH 8
#define SEQ   2048
#define DM    256
#define DI    512
#define DS    16
#define DTR   16
#define NL    4
#define ROWS  (BATCH*SEQ)   // 16384
#define NCH   32            // chunks for the scan
#define CHL   64            // SEQ / NCH

typedef __attribute__((ext_vector_type(8))) __bf16 bh8;
typedef __attribute__((ext_vector_type(4))) float f4;

// ---------- dtype helpers ----------
__device__ __forceinline__ float bf2f(unsigned short u) {
    union { unsigned int i; float f; } v; v.i = ((unsigned int)u) << 16; return v.f;
}
__device__ __forceinline__ float ldg1(const void* p, int i, int bf) {
    if (bf) return bf2f(((const unsigned short*)p)[i]);
    return ((const float*)p)[i];
}
__device__ __forceinline__ float4 ldg4(const void* p, int i, int bf) { // i % 4 == 0
    if (bf) {
        ushort4 q = *(const ushort4*)(((const unsigned short*)p) + i);
        return make_float4(bf2f(q.x), bf2f(q.y), bf2f(q.z), bf2f(q.w));
    }
    return *(const float4*)(((const float*)p) + i);
}
// f32 -> bf16 bits, round-to-nearest-even
__device__ __forceinline__ unsigned short f2bs(float f) {
    union { float f; unsigned u; } x; x.f = f;
    unsigned r = (x.u + 0x7fffu + ((x.u >> 16) & 1u)) >> 16;
    return (unsigned short)r;
}

// ---------- K0: dtype probe ----------
__global__ void k_probe(const void* x, int* flag) {
    int t = threadIdx.x;  // 64 threads
    float v = bf2f(((const unsigned short*)x)[2 * t]);
    int bad = (fabsf(v) < 32.0f) ? 0 : 1;
    for (int o = 1; o < 64; o <<= 1) bad += __shfl_xor(bad, o);
    if (t == 0) *flag = (bad > 8) ? 0 : 1;  // 0 = f32, 1 = bf16
}

// ---------- K1: input projection  h = x @ w_in^T + b_in  (h stays f32) ----------
__global__ __launch_bounds__(256) void k_inproj(const void* x, const void* w_in,
                                                const void* b_in, float* h, const int* flag) {
    int bf = *flag;
    int row = blockIdx.x, e = threadIdx.x;
    float x0 = ldg1(x, row * 2 + 0, bf), x1 = ldg1(x, row * 2 + 1, bf);
    float w0 = ldg1(w_in, e * 2 + 0, bf), w1 = ldg1(w_in, e * 2 + 1, bf);
    float bb = ldg1(b_in, e, bf);
    h[(size_t)row * DM + e] = fmaf(x0, w0, fmaf(x1, w1, bb));
}

// ---------- K2: rmsnorm (f32 in -> bf16 out) ----------
__global__ __launch_bounds__(256) void k_rmsnorm(const float* h, const void* norm_w,
                                                 int w_off, unsigned short* xn, const int* flag) {
    int bf = *flag;
    int wv = threadIdx.x >> 6, ln = threadIdx.x & 63;
    int row = blockIdx.x * 4 + wv;
    float4 v = *(const float4*)(h + (size_t)row * DM + ln * 4);
    float ss = v.x * v.x + v.y * v.y + v.z * v.z + v.w * v.w;
    for (int o = 1; o < 64; o <<= 1) ss += __shfl_xor(ss, o);
    float sc = rsqrtf(ss / DM + 1e-5f);
    float4 w = ldg4(norm_w, w_off + ln * 4, bf);
    ushort4 o4 = { f2bs(v.x * sc * w.x), f2bs(v.y * sc * w.y),
                   f2bs(v.z * sc * w.z), f2bs(v.w * sc * w.w) };
    *(ushort4*)(xn + (size_t)row * DM + ln * 4) = o4;
}

// ---------- K3: bf16 MFMA GEMM  C[M,N] (+)= A[M,K] @ W[N,K]^T ----------
// A is bf16. OBF: bf16 output; ADD: f32 accumulate-into-C.
#define ASTR 72   // LDS row stride (ushorts): 64 + 8 pad
template <int BN, bool ADD, bool OBF>
__global__ __launch_bounds__(256, 2) void k_mfma(const unsigned short* A, const void* W, int w_off,
                                                 void* Cp, int N, int K, const int* flag) {
    int bf = *flag;
    __shared__ unsigned short As[128 * ASTR];
    __shared__ unsigned short Ws[BN * ASTR];
    constexpr int NT = BN / 32;         // col-tiles per wave
    constexpr int WCH = BN * 8 / 256;   // W staging chunks per thread

    int bn = blockIdx.x, bm = blockIdx.y;
    int t = threadIdx.x;
    int w = t >> 6, lane = t & 63;
    int wm = w >> 1, wn = w & 1;
    int lr = lane & 15, quad = lane >> 4;

    f4 acc[4][NT];
#pragma unroll
    for (int i = 0; i < 4; i++)
#pragma unroll
        for (int j = 0; j < NT; j++) acc[i][j] = f4{0.f, 0.f, 0.f, 0.f};

    for (int k0 = 0; k0 < K; k0 += 64) {
        __syncthreads();
        // stage A (bf16 direct copy, 16B per thread-chunk)
#pragma unroll
        for (int i = 0; i < 4; i++) {
            int ch = t + i * 256;
            int r = ch >> 3, kc = (ch & 7) * 8;
            *(uint4*)&As[r * ASTR + kc] =
                *(const uint4*)(A + (size_t)(bm * 128 + r) * K + k0 + kc);
        }
        // stage W (flag-aware)
#pragma unroll
        for (int i = 0; i < WCH; i++) {
            int ch = t + i * 256;
            int r = ch >> 3, kc = (ch & 7) * 8;
            size_t off = (size_t)w_off + (size_t)(bn * BN + r) * K + k0 + kc;
            if (bf) {
                *(uint4*)&Ws[r * ASTR + kc] = *(const uint4*)((const unsigned short*)W + off);
            } else {
                const float* src = (const float*)W + off;
                float4 a0 = *(const float4*)src;
                float4 a1 = *(const float4*)(src + 4);
                ushort4 v0 = { f2bs(a0.x), f2bs(a0.y), f2bs(a0.z), f2bs(a0.w) };
                ushort4 v1 = { f2bs(a1.x), f2bs(a1.y), f2bs(a1.z), f2bs(a1.w) };
                *(ushort4*)&Ws[r * ASTR + kc] = v0;
                *(ushort4*)&Ws[r * ASTR + kc + 4] = v1;
            }
        }
        __syncthreads();
#pragma unroll
        for (int ks = 0; ks < 64; ks += 32) {
            bh8 af[4];
#pragma unroll
            for (int i = 0; i < 4; i++)
                af[i] = *(const bh8*)&As[(wm * 64 + i * 16 + lr) * ASTR + ks + quad * 8];
            bh8 wf[NT];
#pragma unroll
            for (int j = 0; j < NT; j++)
                wf[j] = *(const bh8*)&Ws[(wn * (BN / 2) + j * 16 + lr) * ASTR + ks + quad * 8];
#pragma unroll
            for (int i = 0; i < 4; i++)
#pragma unroll
                for (int j = 0; j < NT; j++)
                    acc[i][j] = __builtin_amdgcn_mfma_f32_16x16x32_bf16(af[i], wf[j], acc[i][j], 0, 0, 0);
        }
    }
    // epilogue: C/D layout col=lane&15, row=quad*4+reg
#pragma unroll
    for (int i = 0; i < 4; i++) {
        int row0 = bm * 128 + wm * 64 + i * 16 + quad * 4;
#pragma unroll
        for (int j = 0; j < NT; j++) {
            int col = bn * BN + wn * (BN / 2) + j * 16 + lr;
#pragma unroll
            for (int r = 0; r < 4; r++) {
                size_t idx = (size_t)(row0 + r) * N + col;
                float v = acc[i][j][r];
                if (ADD) {
                    float* C = (float*)Cp;
                    C[idx] += v;
                } else if (OBF) {
                    ((unsigned short*)Cp)[idx] = f2bs(v);
                } else {
                    ((float*)Cp)[idx] = v;
                }
            }
        }
    }
}

// ---------- K4: causal depthwise conv (k=4) + bias + silu  (bf16 in/out) ----------
__global__ __launch_bounds__(256) void k_conv(const unsigned short* xz, const void* cw, const void* cb,
                                              int layer, unsigned short* u, const int* flag) {
    int bf = *flag;
    int idx = blockIdx.x * 256 + threadIdx.x;  // over ROWS*DI
    int d = idx & (DI - 1);
    int row = idx >> 9;
    int l = row & (SEQ - 1);
    float4 w = ldg4(cw, (layer * DI + d) * 4, bf);
    float acc = ldg1(cb, layer * DI + d, bf);
    const unsigned short* base = xz + (size_t)row * (2 * DI) + d;
    if (l >= 3) acc = fmaf(w.x, bf2f(base[-3 * 2 * DI]), acc);
    if (l >= 2) acc = fmaf(w.y, bf2f(base[-2 * 2 * DI]), acc);
    if (l >= 1) acc = fmaf(w.z, bf2f(base[-1 * 2 * DI]), acc);
    acc = fmaf(w.w, bf2f(base[0]), acc);
    float s = acc / (1.0f + __expf(-acc));  // silu
    u[(size_t)row * DI + d] = f2bs(s);
}

// ---------- K5: x_proj GEMM  dbc[M,48] = u[M,512] @ W[48,512]^T  (u bf16, dbc f32) ----------
__global__ __launch_bounds__(256) void k_xproj(const unsigned short* A, const void* W, int w_off,
                                               float* dbc, const int* flag) {
    int bf = *flag;
    __shared__ float As[16][68];
    __shared__ float Ws[16][52];
    int bm = blockIdx.x;
    int t = threadIdx.x;
    int lr = t >> 2, lk = (t & 3) * 4;
    const unsigned short* Arow = A + (size_t)(bm * 64 + lr) * DI + lk;
    int ty = t >> 4, tx = t & 15;
    float acc[4][3] = {};
    for (int k0 = 0; k0 < DI; k0 += 16) {
        ushort4 a4 = *(const ushort4*)(Arow + k0);
        float4 a = make_float4(bf2f(a4.x), bf2f(a4.y), bf2f(a4.z), bf2f(a4.w));
        float4 w = make_float4(0.f, 0.f, 0.f, 0.f);
        if (t < 192) w = ldg4(W, w_off + lr * DI + k0 + lk, bf);
        __syncthreads();
        As[lk + 0][lr] = a.x; As[lk + 1][lr] = a.y; As[lk + 2][lr] = a.z; As[lk + 3][lr] = a.w;
        if (t < 192) { Ws[lk + 0][lr] = w.x; Ws[lk + 1][lr] = w.y; Ws[lk + 2][lr] = w.z; Ws[lk + 3][lr] = w.w; }
        __syncthreads();
#pragma unroll
        for (int kk = 0; kk < 16; kk++) {
            float4 av = *(const float4*)&As[kk][ty * 4];
            float w0 = Ws[kk][tx * 3 + 0], w1 = Ws[kk][tx * 3 + 1], w2 = Ws[kk][tx * 3 + 2];
            acc[0][0] = fmaf(av.x, w0, acc[0][0]); acc[0][1] = fmaf(av.x, w1, acc[0][1]); acc[0][2] = fmaf(av.x, w2, acc[0][2]);
            acc[1][0] = fmaf(av.y, w0, acc[1][0]); acc[1][1] = fmaf(av.y, w1, acc[1][1]); acc[1][2] = fmaf(av.y, w2, acc[1][2]);
            acc[2][0] = fmaf(av.z, w0, acc[2][0]); acc[2][1] = fmaf(av.z, w1, acc[2][1]); acc[2][2] = fmaf(av.z, w2, acc[2][2]);
            acc[3][0] = fmaf(av.w, w0, acc[3][0]); acc[3][1] = fmaf(av.w, w1, acc[3][1]); acc[3][2] = fmaf(av.w, w2, acc[3][2]);
        }
    }
#pragma unroll
    for (int i = 0; i < 4; i++) {
        int row = bm * 64 + ty * 4 + i;
#pragma unroll
        for (int j = 0; j < 3; j++) dbc[(size_t)row * 48 + tx * 3 + j] = acc[i][j];
    }
}

// ---------- K6: dt projection + softplus  (delta -> bf16) ----------
__global__ __launch_bounds__(256) void k_dt(const float* dbc, const void* dtw, const void* dtb,
                                            int layer, unsigned short* delta, const int* flag) {
    int bf = *flag;
    int row = blockIdx.x;
    int t = threadIdx.x;
    __shared__ float s[16];
    if (t < 16) s[t] = dbc[(size_t)row * 48 + t];
    __syncthreads();
#pragma unroll
    for (int p = 0; p < 2; p++) {
        int d = t + p * 256;
        float acc = ldg1(dtb, layer * DI + d, bf);
#pragma unroll
        for (int kq = 0; kq < 4; kq++) {
            float4 w = ldg4(dtw, (layer * DI + d) * 16 + kq * 4, bf);
            acc = fmaf(s[kq * 4 + 0], w.x, acc);
            acc = fmaf(s[kq * 4 + 1], w.y, acc);
            acc = fmaf(s[kq * 4 + 2], w.z, acc);
            acc = fmaf(s[kq * 4 + 3], w.w, acc);
        }
        float sp = (acc > 20.0f) ? acc : log1pf(__expf(acc));  // softplus
        delta[(size_t)row * DI + d] = f2bs(sp);
    }
}

// ---------- K7a: scan pass 1 — per-chunk transition product P and zero-init endpoint E ----------
__global__ __launch_bounds__(256) void k_scan1(const unsigned short* delta, const unsigned short* u,
                                               const float* dbc, const void* A_log, float* P, float* E,
                                               int layer, const int* flag) {
    int bf = *flag;
    int x = blockIdx.x;                 // 512 = b(8) * c(32) * dg(2)
    int dg = x & 1, c = (x >> 1) & (NCH - 1), b = x >> 6;
    int tid = threadIdx.x;
    int d = dg * 256 + tid;
    int t0 = c * CHL;

    __shared__ float sB[CHL][16];
    {
        int r = tid >> 2, q = tid & 3;
        *(float4*)&sB[r][q * 4] =
            *(const float4*)(dbc + ((size_t)b * SEQ + t0 + r) * 48 + DTR + q * 4);
    }

    float A[16];
#pragma unroll
    for (int n4 = 0; n4 < 4; n4++) {
        float4 a4 = ldg4(A_log, (layer * DI + d) * DS + n4 * 4, bf);
        A[n4 * 4 + 0] = -__expf(a4.x);
        A[n4 * 4 + 1] = -__expf(a4.y);
        A[n4 * 4 + 2] = -__expf(a4.z);
        A[n4 * 4 + 3] = -__expf(a4.w);
    }
    float h[16];
    float Pp[16];
#pragma unroll
    for (int n = 0; n < 16; n++) { h[n] = 0.0f; Pp[n] = 1.0f; }

    const unsigned short* dp = delta + ((size_t)b * SEQ + t0) * DI + d;
    const unsigned short* up = u + ((size_t)b * SEQ + t0) * DI + d;

    float dl0[4], uu0[4];
#pragma unroll
    for (int j = 0; j < 4; j++) { dl0[j] = bf2f(dp[j * DI]); uu0[j] = bf2f(up[j * DI]); }
    __syncthreads();

    for (int s = 0; s < CHL / 4; s++) {
        int sn = (s + 1 < CHL / 4) ? (s + 1) : s;     // clamped prefetch
        float dl1[4], uu1[4];
#pragma unroll
        for (int j = 0; j < 4; j++) {
            dl1[j] = bf2f(dp[(sn * 4 + j) * DI]);
            uu1[j] = bf2f(up[(sn * 4 + j) * DI]);
        }
#pragma unroll
        for (int j = 0; j < 4; j++) {
            int t = s * 4 + j;
            float dlt = dl0[j], uu = uu0[j];
            float du = dlt * uu;
#pragma unroll
            for (int n4 = 0; n4 < 4; n4++) {
                float4 Bv = *(const float4*)&sB[t][n4 * 4];
                int n = n4 * 4;
                float a0 = __expf(dlt * A[n + 0]); h[n + 0] = fmaf(a0, h[n + 0], du * Bv.x); Pp[n + 0] *= a0;
                float a1 = __expf(dlt * A[n + 1]); h[n + 1] = fmaf(a1, h[n + 1], du * Bv.y); Pp[n + 1] *= a1;
                float a2 = __expf(dlt * A[n + 2]); h[n + 2] = fmaf(a2, h[n + 2], du * Bv.z); Pp[n + 2] *= a2;
                float a3 = __expf(dlt * A[n + 3]); h[n + 3] = fmaf(a3, h[n + 3], du * Bv.w); Pp[n + 3] *= a3;
            }
        }
#pragma unroll
        for (int j = 0; j < 4; j++) { dl0[j] = dl1[j]; uu0[j] = uu1[j]; }
    }
    float* Pd = P + (((size_t)b * NCH + c) * DI + d) * DS;
    float* Ed = E + (((size_t)b * NCH + c) * DI + d) * DS;
#pragma unroll
    for (int n4 = 0; n4 < 4; n4++) {
        *(float4*)(Pd + n4 * 4) = make_float4(Pp[n4 * 4], Pp[n4 * 4 + 1], Pp[n4 * 4 + 2], Pp[n4 * 4 + 3]);
        *(float4*)(Ed + n4 * 4) = make_float4(h[n4 * 4], h[n4 * 4 + 1], h[n4 * 4 + 2], h[n4 * 4 + 3]);
    }
}

// ---------- K7b: stitch ----------
__global__ __launch_bounds__(256) void k_stitch(float* P, float* E) {
    int g = blockIdx.x * 256 + threadIdx.x;   // 65536 threads over b(8) * d(512) * n(16)
    int b = g >> 13, r = g & 8191;
    size_t base = (size_t)b * NCH * (DI * DS) + r;
    float H = 0.0f;
#pragma unroll 4
    for (int c = 0; c < NCH; c++) {
        size_t idx = base + (size_t)c * (DI * DS);
        float p = P[idx], e = E[idx];
        E[idx] = H;                 // incoming state for chunk c
        H = fmaf(p, H, e);
    }
}

// ---------- K7c: scan pass 2 — full scan within chunk, emit y*silu(z) (bf16 out) ----------
__global__ __launch_bounds__(256) void k_scan2(const unsigned short* delta, const unsigned short* u,
                                               const float* dbc, const void* A_log, const void* D_skip,
                                               const unsigned short* xz, const float* E,
                                               unsigned short* g, int layer, const int* flag) {
    int bf = *flag;
    int x = blockIdx.x;
    int dg = x & 1, c = (x >> 1) & (NCH - 1), b = x >> 6;
    int tid = threadIdx.x;
    int d = dg * 256 + tid;
    int t0 = c * CHL;

    __shared__ float sBC[CHL][32];   // [t][0..15]=B, [16..31]=C
#pragma unroll
    for (int k2 = 0; k2 < 2; k2++) {
        int fi = k2 * 256 + tid;
        int r = fi >> 3, q = fi & 7;
        *(float4*)&sBC[r][q * 4] =
            *(const float4*)(dbc + ((size_t)b * SEQ + t0 + r) * 48 + DTR + q * 4);
    }

    float A[16];
#pragma unroll
    for (int n4 = 0; n4 < 4; n4++) {
        float4 a4 = ldg4(A_log, (layer * DI + d) * DS + n4 * 4, bf);
        A[n4 * 4 + 0] = -__expf(a4.x);
        A[n4 * 4 + 1] = -__expf(a4.y);
        A[n4 * 4 + 2] = -__expf(a4.z);
        A[n4 * 4 + 3] = -__expf(a4.w);
    }
    float Dp = ldg1(D_skip, layer * DI + d, bf);

    float h[16];
    const float* E0 = E + (((size_t)b * NCH + c) * DI + d) * DS;
#pragma unroll
    for (int n4 = 0; n4 < 4; n4++) {
        float4 h4 = *(const float4*)(E0 + n4 * 4);
        h[n4 * 4 + 0] = h4.x; h[n4 * 4 + 1] = h4.y; h[n4 * 4 + 2] = h4.z; h[n4 * 4 + 3] = h4.w;
    }

    const unsigned short* dp = delta + ((size_t)b * SEQ + t0) * DI + d;
    const unsigned short* up = u + ((size_t)b * SEQ + t0) * DI + d;
    const unsigned short* zp = xz + ((size_t)b * SEQ + t0) * (2 * DI) + DI + d;
    unsigned short* gp = g + ((size_t)b * SEQ + t0) * DI + d;

    float dl0[4], uu0[4], zz0[4];
#pragma unroll
    for (int j = 0; j < 4; j++) {
        dl0[j] = bf2f(dp[j * DI]); uu0[j] = bf2f(up[j * DI]); zz0[j] = bf2f(zp[j * (2 * DI)]);
    }
    __syncthreads();

    for (int s = 0; s < CHL / 4; s++) {
        int sn = (s + 1 < CHL / 4) ? (s + 1) : s;
        float dl1[4], uu1[4], zz1[4];
#pragma unroll
        for (int j = 0; j < 4; j++) {
            dl1[j] = bf2f(dp[(sn * 4 + j) * DI]);
            uu1[j] = bf2f(up[(sn * 4 + j) * DI]);
            zz1[j] = bf2f(zp[(sn * 4 + j) * (2 * DI)]);
        }
#pragma unroll
        for (int j = 0; j < 4; j++) {
            int t = s * 4 + j;
            float dlt = dl0[j], uu = uu0[j], zz = zz0[j];
            float du = dlt * uu;
            float y = 0.0f;
#pragma unroll
            for (int n4 = 0; n4 < 4; n4++) {
                float4 Bv = *(const float4*)&sBC[t][n4 * 4];
                float4 Cv = *(const float4*)&sBC[t][16 + n4 * 4];
                int n = n4 * 4;
                float a0 = __expf(dlt * A[n + 0]); h[n + 0] = fmaf(a0, h[n + 0], du * Bv.x); y = fmaf(Cv.x, h[n + 0], y);
                float a1 = __expf(dlt * A[n + 1]); h[n + 1] = fmaf(a1, h[n + 1], du * Bv.y); y = fmaf(Cv.y, h[n + 1], y);
                float a2 = __expf(dlt * A[n + 2]); h[n + 2] = fmaf(a2, h[n + 2], du * Bv.z); y = fmaf(Cv.z, h[n + 2], y);
                float a3 = __expf(dlt * A[n + 3]); h[n + 3] = fmaf(a3, h[n + 3], du * Bv.w); y = fmaf(Cv.w, h[n + 3], y);
            }
            float yt = fmaf(uu, Dp, y);
            float sg = zz / (1.0f + __expf(-zz));
            gp[(size_t)t * DI] = f2bs(yt * sg);
        }
#pragma unroll
        for (int j = 0; j < 4; j++) { dl0[j] = dl1[j]; uu0[j] = uu1[j]; zz0[j] = zz1[j]; }
    }
}

// ---------- K9: head ----------
__global__ __launch_bounds__(256) void k_head(const float* h, const void* w_head, const void* b_head,
                                              void* out, const int* flag) {
    int bf = *flag;
    int wv = threadIdx.x >> 6, ln = threadIdx.x & 63;
    int row = blockIdx.x * 4 + wv;
    float4 v = *(const float4*)(h + (size_t)row * DM + ln * 4);
    float4 w = ldg4(w_head, ln * 4, bf);
    float s = v.x * w.x + v.y * w.y + v.z * w.z + v.w * w.w;
    for (int o = 1; o < 64; o <<= 1) s += __shfl_xor(s, o);
    if (ln == 0) {
        s += ldg1(b_head, 0, bf);
        if (bf) ((__hip_bfloat16*)out)[row] = __float2bfloat16(s);
        else    ((float*)out)[row] = s;
    }
}

extern "C" void kernel_launch(void* const* d_in, const int* in_sizes, int n_in,
                              void* d_out, int out_size, void* d_ws, size_t ws_size,
                              hipStream_t stream) {
    (void)in_sizes; (void)n_in; (void)out_size; (void)ws_size;
    const void* x      = d_in[0];
    const void* w_in   = d_in[1];
    const void* b_in   = d_in[2];
    const void* norm_w = d_in[3];
    const void* ipw    = d_in[4];
    const void* cw     = d_in[5];
    const void* cb     = d_in[6];
    const void* xpw    = d_in[7];
    const void* dtw    = d_in[8];
    const void* dtb    = d_in[9];
    const void* A_log  = d_in[10];
    const void* D_skip = d_in[11];
    const void* opw    = d_in[12];
    const void* w_head = d_in[13];
    const void* b_head = d_in[14];

    // layout kept in float-units for simplicity (bf16 buffers under-fill their slots)
    float* ws    = (float*)d_ws;
    float*          h     = ws;                           // f32, 4,194,304
    unsigned short* xn    = (unsigned short*)(h + 4194304);   // bf16 (slot 4,194,304 floats; P/E alias)
    unsigned short* xz    = (unsigned short*)(ws + 8388608);  // bf16 in 16,777,216-float slot
    unsigned short* u     = (unsigned short*)(ws + 25165824); // bf16
    float*          dbc   = ws + 33554432;                // f32, 786,432
    unsigned short* delta = (unsigned short*)(ws + 34340864); // bf16
    int*            flag  = (int*)(ws + 42729472);

    float* P = (float*)xn;              // 2,097,152 f32
    float* E = (float*)xn + 2097152;    // 2,097,152 f32 (xn slot exactly fits; xn is dead during scan)

    k_probe<<<1, 64, 0, stream>>>(x, flag);
    k_inproj<<<ROWS, 256, 0, stream>>>(x, w_in, b_in, h, flag);

    for (int layer = 0; layer < NL; layer++) {
        k_rmsnorm<<<ROWS / 4, 256, 0, stream>>>(h, norm_w, layer * DM, xn, flag);
        k_mfma<128, false, true><<<dim3(2 * DI / 128, ROWS / 128), 256, 0, stream>>>(
            xn, ipw, layer * 2 * DI * DM, xz, 2 * DI, DM, flag);
        k_conv<<<ROWS * DI / 256, 256, 0, stream>>>(xz, cw, cb, layer, u, flag);
        k_xproj<<<ROWS / 64, 256, 0, stream>>>(u, xpw, layer * 48 * DI, dbc, flag);
        k_dt<<<ROWS, 256, 0, stream>>>(dbc, dtw, dtb, layer, delta, flag);
        k_scan1<<<BATCH * NCH * 2, 256, 0, stream>>>(delta, u, dbc, A_log, P, E, layer, flag);
        k_stitch<<<BATCH * DI * DS / 256, 256, 0, stream>>>(P, E);
        k_scan2<<<BATCH * NCH * 2, 256, 0, stream>>>(delta, u, dbc, A_log, D_skip, xz, E,
                                                     u /*g aliases u*/, layer, flag);
        k_mfma<64, true, false><<<dim3(DM / 64, ROWS / 128), 256, 0, stream>>>(
            u, opw, layer * DM * DI, h, DM, DI, flag);
    }

    k_head<<<ROWS / 4, 256, 0, stream>>>(h, w_head, b_head, d_out, flag);
}

// Round 5
// 991.611 us; speedup vs baseline: 3.0086x; 1.0456x over previous
//
#include <hip/hip_runtime.h>
#include <hip/hip_bf16.h>

#define BATCH 8
#define SEQ   2048
#define DM    256
#define DI    512
#define DS    16
#define DTR   16
#define NL    4
#define ROWS  (BATCH*SEQ)   // 16384
#define NCH   32            // chunks for the scan
#define CHL   64            // SEQ / NCH
#define NF    576           // fused x_proj/dt GEMM width: 512 delta + 32 BC + 32 pad

typedef __attribute__((ext_vector_type(8))) __bf16 bh8;
typedef __attribute__((ext_vector_type(4))) float f4;

// ---------- dtype helpers ----------
__device__ __forceinline__ float bf2f(unsigned short u) {
    union { unsigned int i; float f; } v; v.i = ((unsigned int)u) << 16; return v.f;
}
__device__ __forceinline__ float ldg1(const void* p, int i, int bf) {
    if (bf) return bf2f(((const unsigned short*)p)[i]);
    return ((const float*)p)[i];
}
__device__ __forceinline__ float4 ldg4(const void* p, int i, int bf) { // i % 4 == 0
    if (bf) {
        ushort4 q = *(const ushort4*)(((const unsigned short*)p) + i);
        return make_float4(bf2f(q.x), bf2f(q.y), bf2f(q.z), bf2f(q.w));
    }
    return *(const float4*)(((const float*)p) + i);
}
// f32 -> bf16 bits, round-to-nearest-even
__device__ __forceinline__ unsigned short f2bs(float f) {
    union { float f; unsigned u; } x; x.f = f;
    unsigned r = (x.u + 0x7fffu + ((x.u >> 16) & 1u)) >> 16;
    return (unsigned short)r;
}

// ---------- K0: dtype probe ----------
__global__ void k_probe(const void* x, int* flag) {
    int t = threadIdx.x;  // 64 threads
    float v = bf2f(((const unsigned short*)x)[2 * t]);
    int bad = (fabsf(v) < 32.0f) ? 0 : 1;
    for (int o = 1; o < 64; o <<= 1) bad += __shfl_xor(bad, o);
    if (t == 0) *flag = (bad > 8) ? 0 : 1;  // 0 = f32, 1 = bf16
}

// ---------- K-prep: composite weight Wcomb[l][576][512] (bf16) ----------
// rows 0..511:  W_delta[d,k] = sum_j dtw[l,d,j] * xpw[l,j,k]
// rows 512..543: xpw[l, 16+(r-512), k]
// rows 544..575: 0
__global__ __launch_bounds__(256) void k_prep(const void* dtw, const void* xpw,
                                              unsigned short* Wc, const int* flag) {
    int bf = *flag;
    int blk = blockIdx.x;           // 4 * 576
    int l = blk / NF, r = blk % NF;
    int t = threadIdx.x;
    unsigned short* out = Wc + ((size_t)l * NF + r) * DI;
#pragma unroll
    for (int p = 0; p < 2; p++) {
        int k = t + p * 256;
        float v = 0.0f;
        if (r < 512) {
            const int db = l * DI * DTR + r * DTR;
            const int xb = l * 48 * DI;
#pragma unroll
            for (int j = 0; j < 16; j++)
                v = fmaf(ldg1(dtw, db + j, bf), ldg1(xpw, xb + j * DI + k, bf), v);
        } else if (r < 544) {
            v = ldg1(xpw, l * 48 * DI + (16 + r - 512) * DI + k, bf);
        }
        out[k] = f2bs(v);
    }
}

// ---------- K1: input projection  h = x @ w_in^T + b_in  (h stays f32) ----------
__global__ __launch_bounds__(256) void k_inproj(const void* x, const void* w_in,
                                                const void* b_in, float* h, const int* flag) {
    int bf = *flag;
    int row = blockIdx.x, e = threadIdx.x;
    float x0 = ldg1(x, row * 2 + 0, bf), x1 = ldg1(x, row * 2 + 1, bf);
    float w0 = ldg1(w_in, e * 2 + 0, bf), w1 = ldg1(w_in, e * 2 + 1, bf);
    float bb = ldg1(b_in, e, bf);
    h[(size_t)row * DM + e] = fmaf(x0, w0, fmaf(x1, w1, bb));
}

// ---------- K2: rmsnorm (f32 in -> bf16 out) ----------
__global__ __launch_bounds__(256) void k_rmsnorm(const float* h, const void* norm_w,
                                                 int w_off, unsigned short* xn, const int* flag) {
    int bf = *flag;
    int wv = threadIdx.x >> 6, ln = threadIdx.x & 63;
    int row = blockIdx.x * 4 + wv;
    float4 v = *(const float4*)(h + (size_t)row * DM + ln * 4);
    float ss = v.x * v.x + v.y * v.y + v.z * v.z + v.w * v.w;
    for (int o = 1; o < 64; o <<= 1) ss += __shfl_xor(ss, o);
    float sc = rsqrtf(ss / DM + 1e-5f);
    float4 w = ldg4(norm_w, w_off + ln * 4, bf);
    ushort4 o4 = { f2bs(v.x * sc * w.x), f2bs(v.y * sc * w.y),
                   f2bs(v.z * sc * w.z), f2bs(v.w * sc * w.w) };
    *(ushort4*)(xn + (size_t)row * DM + ln * 4) = o4;
}

// ---------- K3: bf16 MFMA GEMM  C[M,N] (+)= A[M,K] @ W[N,K]^T ----------
#define ASTR 72   // LDS row stride (ushorts): 64 + 8 pad
template <int BN, bool ADD, bool OBF>
__global__ __launch_bounds__(256, 2) void k_mfma(const unsigned short* A, const void* W, int w_off,
                                                 void* Cp, int N, int K, const int* flag) {
    int bf = *flag;
    __shared__ unsigned short As[128 * ASTR];
    __shared__ unsigned short Ws[BN * ASTR];
    constexpr int NT = BN / 32;         // col-tiles per wave
    constexpr int WCH = BN * 8 / 256;   // W staging chunks per thread

    int bn = blockIdx.x, bm = blockIdx.y;
    int t = threadIdx.x;
    int w = t >> 6, lane = t & 63;
    int wm = w >> 1, wn = w & 1;
    int lr = lane & 15, quad = lane >> 4;

    f4 acc[4][NT];
#pragma unroll
    for (int i = 0; i < 4; i++)
#pragma unroll
        for (int j = 0; j < NT; j++) acc[i][j] = f4{0.f, 0.f, 0.f, 0.f};

    for (int k0 = 0; k0 < K; k0 += 64) {
        __syncthreads();
#pragma unroll
        for (int i = 0; i < 4; i++) {
            int ch = t + i * 256;
            int r = ch >> 3, kc = (ch & 7) * 8;
            *(uint4*)&As[r * ASTR + kc] =
                *(const uint4*)(A + (size_t)(bm * 128 + r) * K + k0 + kc);
        }
#pragma unroll
        for (int i = 0; i < WCH; i++) {
            int ch = t + i * 256;
            int r = ch >> 3, kc = (ch & 7) * 8;
            size_t off = (size_t)w_off + (size_t)(bn * BN + r) * K + k0 + kc;
            if (bf) {
                *(uint4*)&Ws[r * ASTR + kc] = *(const uint4*)((const unsigned short*)W + off);
            } else {
                const float* src = (const float*)W + off;
                float4 a0 = *(const float4*)src;
                float4 a1 = *(const float4*)(src + 4);
                ushort4 v0 = { f2bs(a0.x), f2bs(a0.y), f2bs(a0.z), f2bs(a0.w) };
                ushort4 v1 = { f2bs(a1.x), f2bs(a1.y), f2bs(a1.z), f2bs(a1.w) };
                *(ushort4*)&Ws[r * ASTR + kc] = v0;
                *(ushort4*)&Ws[r * ASTR + kc + 4] = v1;
            }
        }
        __syncthreads();
#pragma unroll
        for (int ks = 0; ks < 64; ks += 32) {
            bh8 af[4];
#pragma unroll
            for (int i = 0; i < 4; i++)
                af[i] = *(const bh8*)&As[(wm * 64 + i * 16 + lr) * ASTR + ks + quad * 8];
            bh8 wf[NT];
#pragma unroll
            for (int j = 0; j < NT; j++)
                wf[j] = *(const bh8*)&Ws[(wn * (BN / 2) + j * 16 + lr) * ASTR + ks + quad * 8];
#pragma unroll
            for (int i = 0; i < 4; i++)
#pragma unroll
                for (int j = 0; j < NT; j++)
                    acc[i][j] = __builtin_amdgcn_mfma_f32_16x16x32_bf16(af[i], wf[j], acc[i][j], 0, 0, 0);
        }
    }
#pragma unroll
    for (int i = 0; i < 4; i++) {
        int row0 = bm * 128 + wm * 64 + i * 16 + quad * 4;
#pragma unroll
        for (int j = 0; j < NT; j++) {
            int col = bn * BN + wn * (BN / 2) + j * 16 + lr;
#pragma unroll
            for (int r = 0; r < 4; r++) {
                size_t idx = (size_t)(row0 + r) * N + col;
                float v = acc[i][j][r];
                if (ADD) {
                    ((float*)Cp)[idx] += v;
                } else if (OBF) {
                    ((unsigned short*)Cp)[idx] = f2bs(v);
                } else {
                    ((float*)Cp)[idx] = v;
                }
            }
        }
    }
}

// ---------- K-fused: u @ Wcomb^T -> delta (softplus, bf16) + BC (f32 [ROWS,32]) ----------
// BN=64; Wcomb always bf16. N logical = 576, K = 512.
__global__ __launch_bounds__(256, 2) void k_fused(const unsigned short* A, const unsigned short* Wc,
                                                  int w_off, unsigned short* delta, float* BC,
                                                  const void* dtb, int layer, const int* flag) {
    int bf = *flag;
    __shared__ unsigned short As[128 * ASTR];
    __shared__ unsigned short Ws[64 * ASTR];

    int bn = blockIdx.x, bm = blockIdx.y;
    int t = threadIdx.x;
    int w = t >> 6, lane = t & 63;
    int wm = w >> 1, wn = w & 1;
    int lr = lane & 15, quad = lane >> 4;

    f4 acc[4][2];
#pragma unroll
    for (int i = 0; i < 4; i++)
#pragma unroll
        for (int j = 0; j < 2; j++) acc[i][j] = f4{0.f, 0.f, 0.f, 0.f};

    for (int k0 = 0; k0 < DI; k0 += 64) {
        __syncthreads();
#pragma unroll
        for (int i = 0; i < 4; i++) {
            int ch = t + i * 256;
            int r = ch >> 3, kc = (ch & 7) * 8;
            *(uint4*)&As[r * ASTR + kc] =
                *(const uint4*)(A + (size_t)(bm * 128 + r) * DI + k0 + kc);
        }
#pragma unroll
        for (int i = 0; i < 2; i++) {
            int ch = t + i * 256;
            int r = ch >> 3, kc = (ch & 7) * 8;
            *(uint4*)&Ws[r * ASTR + kc] =
                *(const uint4*)(Wc + (size_t)w_off + (size_t)(bn * 64 + r) * DI + k0 + kc);
        }
        __syncthreads();
#pragma unroll
        for (int ks = 0; ks < 64; ks += 32) {
            bh8 af[4];
#pragma unroll
            for (int i = 0; i < 4; i++)
                af[i] = *(const bh8*)&As[(wm * 64 + i * 16 + lr) * ASTR + ks + quad * 8];
            bh8 wf[2];
#pragma unroll
            for (int j = 0; j < 2; j++)
                wf[j] = *(const bh8*)&Ws[(wn * 32 + j * 16 + lr) * ASTR + ks + quad * 8];
#pragma unroll
            for (int i = 0; i < 4; i++)
#pragma unroll
                for (int j = 0; j < 2; j++)
                    acc[i][j] = __builtin_amdgcn_mfma_f32_16x16x32_bf16(af[i], wf[j], acc[i][j], 0, 0, 0);
        }
    }
#pragma unroll
    for (int i = 0; i < 4; i++) {
        int row0 = bm * 128 + wm * 64 + i * 16 + quad * 4;
#pragma unroll
        for (int j = 0; j < 2; j++) {
            int col = bn * 64 + wn * 32 + j * 16 + lr;
            if (col < 512) {
                float bb = ldg1(dtb, layer * DI + col, bf);
#pragma unroll
                for (int r = 0; r < 4; r++) {
                    float v = acc[i][j][r] + bb;
                    float sp = (v > 20.0f) ? v : log1pf(__expf(v));
                    delta[(size_t)(row0 + r) * DI + col] = f2bs(sp);
                }
            } else if (col < 544) {
#pragma unroll
                for (int r = 0; r < 4; r++)
                    BC[(size_t)(row0 + r) * 32 + (col - 512)] = acc[i][j][r];
            }
        }
    }
}

// ---------- K4: causal depthwise conv (k=4) + bias + silu  (bf16 in/out) ----------
__global__ __launch_bounds__(256) void k_conv(const unsigned short* xz, const void* cw, const void* cb,
                                              int layer, unsigned short* u, const int* flag) {
    int bf = *flag;
    int idx = blockIdx.x * 256 + threadIdx.x;  // over ROWS*DI
    int d = idx & (DI - 1);
    int row = idx >> 9;
    int l = row & (SEQ - 1);
    float4 w = ldg4(cw, (layer * DI + d) * 4, bf);
    float acc = ldg1(cb, layer * DI + d, bf);
    const unsigned short* base = xz + (size_t)row * (2 * DI) + d;
    if (l >= 3) acc = fmaf(w.x, bf2f(base[-3 * 2 * DI]), acc);
    if (l >= 2) acc = fmaf(w.y, bf2f(base[-2 * 2 * DI]), acc);
    if (l >= 1) acc = fmaf(w.z, bf2f(base[-1 * 2 * DI]), acc);
    acc = fmaf(w.w, bf2f(base[0]), acc);
    float s = acc / (1.0f + __expf(-acc));  // silu
    u[(size_t)row * DI + d] = f2bs(s);
}

// ---------- K7a: scan pass 1 ----------
__global__ __launch_bounds__(256) void k_scan1(const unsigned short* delta, const unsigned short* u,
                                               const float* BC, const void* A_log, float* P, float* E,
                                               int layer, const int* flag) {
    int bf = *flag;
    int x = blockIdx.x;                 // 512 = b(8) * c(32) * dg(2)
    int dg = x & 1, c = (x >> 1) & (NCH - 1), b = x >> 6;
    int tid = threadIdx.x;
    int d = dg * 256 + tid;
    int t0 = c * CHL;

    __shared__ float sB[CHL][16];
    {
        int r = tid >> 2, q = tid & 3;
        *(float4*)&sB[r][q * 4] =
            *(const float4*)(BC + ((size_t)b * SEQ + t0 + r) * 32 + q * 4);
    }

    float A[16];
#pragma unroll
    for (int n4 = 0; n4 < 4; n4++) {
        float4 a4 = ldg4(A_log, (layer * DI + d) * DS + n4 * 4, bf);
        A[n4 * 4 + 0] = -__expf(a4.x);
        A[n4 * 4 + 1] = -__expf(a4.y);
        A[n4 * 4 + 2] = -__expf(a4.z);
        A[n4 * 4 + 3] = -__expf(a4.w);
    }
    float h[16];
    float Pp[16];
#pragma unroll
    for (int n = 0; n < 16; n++) { h[n] = 0.0f; Pp[n] = 1.0f; }

    const unsigned short* dp = delta + ((size_t)b * SEQ + t0) * DI + d;
    const unsigned short* up = u + ((size_t)b * SEQ + t0) * DI + d;

    float dl0[4], uu0[4];
#pragma unroll
    for (int j = 0; j < 4; j++) { dl0[j] = bf2f(dp[j * DI]); uu0[j] = bf2f(up[j * DI]); }
    __syncthreads();

    for (int s = 0; s < CHL / 4; s++) {
        int sn = (s + 1 < CHL / 4) ? (s + 1) : s;     // clamped prefetch
        float dl1[4], uu1[4];
#pragma unroll
        for (int j = 0; j < 4; j++) {
            dl1[j] = bf2f(dp[(sn * 4 + j) * DI]);
            uu1[j] = bf2f(up[(sn * 4 + j) * DI]);
        }
#pragma unroll
        for (int j = 0; j < 4; j++) {
            int t = s * 4 + j;
            float dlt = dl0[j], uu = uu0[j];
            float du = dlt * uu;
#pragma unroll
            for (int n4 = 0; n4 < 4; n4++) {
                float4 Bv = *(const float4*)&sB[t][n4 * 4];
                int n = n4 * 4;
                float a0 = __expf(dlt * A[n + 0]); h[n + 0] = fmaf(a0, h[n + 0], du * Bv.x); Pp[n + 0] *= a0;
                float a1 = __expf(dlt * A[n + 1]); h[n + 1] = fmaf(a1, h[n + 1], du * Bv.y); Pp[n + 1] *= a1;
                float a2 = __expf(dlt * A[n + 2]); h[n + 2] = fmaf(a2, h[n + 2], du * Bv.z); Pp[n + 2] *= a2;
                float a3 = __expf(dlt * A[n + 3]); h[n + 3] = fmaf(a3, h[n + 3], du * Bv.w); Pp[n + 3] *= a3;
            }
        }
#pragma unroll
        for (int j = 0; j < 4; j++) { dl0[j] = dl1[j]; uu0[j] = uu1[j]; }
    }
    float* Pd = P + (((size_t)b * NCH + c) * DI + d) * DS;
    float* Ed = E + (((size_t)b * NCH + c) * DI + d) * DS;
#pragma unroll
    for (int n4 = 0; n4 < 4; n4++) {
        *(float4*)(Pd + n4 * 4) = make_float4(Pp[n4 * 4], Pp[n4 * 4 + 1], Pp[n4 * 4 + 2], Pp[n4 * 4 + 3]);
        *(float4*)(Ed + n4 * 4) = make_float4(h[n4 * 4], h[n4 * 4 + 1], h[n4 * 4 + 2], h[n4 * 4 + 3]);
    }
}

// ---------- K7b: stitch ----------
__global__ __launch_bounds__(256) void k_stitch(float* P, float* E) {
    int g = blockIdx.x * 256 + threadIdx.x;   // 65536 threads over b(8) * d(512) * n(16)
    int b = g >> 13, r = g & 8191;
    size_t base = (size_t)b * NCH * (DI * DS) + r;
    float H = 0.0f;
#pragma unroll 4
    for (int c = 0; c < NCH; c++) {
        size_t idx = base + (size_t)c * (DI * DS);
        float p = P[idx], e = E[idx];
        E[idx] = H;                 // incoming state for chunk c
        H = fmaf(p, H, e);
    }
}

// ---------- K7c: scan pass 2 ----------
__global__ __launch_bounds__(256) void k_scan2(const unsigned short* delta, const unsigned short* u,
                                               const float* BC, const void* A_log, const void* D_skip,
                                               const unsigned short* xz, const float* E,
                                               unsigned short* g, int layer, const int* flag) {
    int bf = *flag;
    int x = blockIdx.x;
    int dg = x & 1, c = (x >> 1) & (NCH - 1), b = x >> 6;
    int tid = threadIdx.x;
    int d = dg * 256 + tid;
    int t0 = c * CHL;

    __shared__ float sBC[CHL][32];   // [t][0..15]=B, [16..31]=C
#pragma unroll
    for (int k2 = 0; k2 < 2; k2++) {
        int fi = k2 * 256 + tid;
        int r = fi >> 3, q = fi & 7;
        *(float4*)&sBC[r][q * 4] =
            *(const float4*)(BC + ((size_t)b * SEQ + t0 + r) * 32 + q * 4);
    }

    float A[16];
#pragma unroll
    for (int n4 = 0; n4 < 4; n4++) {
        float4 a4 = ldg4(A_log, (layer * DI + d) * DS + n4 * 4, bf);
        A[n4 * 4 + 0] = -__expf(a4.x);
        A[n4 * 4 + 1] = -__expf(a4.y);
        A[n4 * 4 + 2] = -__expf(a4.z);
        A[n4 * 4 + 3] = -__expf(a4.w);
    }
    float Dp = ldg1(D_skip, layer * DI + d, bf);

    float h[16];
    const float* E0 = E + (((size_t)b * NCH + c) * DI + d) * DS;
#pragma unroll
    for (int n4 = 0; n4 < 4; n4++) {
        float4 h4 = *(const float4*)(E0 + n4 * 4);
        h[n4 * 4 + 0] = h4.x; h[n4 * 4 + 1] = h4.y; h[n4 * 4 + 2] = h4.z; h[n4 * 4 + 3] = h4.w;
    }

    const unsigned short* dp = delta + ((size_t)b * SEQ + t0) * DI + d;
    const unsigned short* up = u + ((size_t)b * SEQ + t0) * DI + d;
    const unsigned short* zp = xz + ((size_t)b * SEQ + t0) * (2 * DI) + DI + d;
    unsigned short* gp = g + ((size_t)b * SEQ + t0) * DI + d;

    float dl0[4], uu0[4], zz0[4];
#pragma unroll
    for (int j = 0; j < 4; j++) {
        dl0[j] = bf2f(dp[j * DI]); uu0[j] = bf2f(up[j * DI]); zz0[j] = bf2f(zp[j * (2 * DI)]);
    }
    __syncthreads();

    for (int s = 0; s < CHL / 4; s++) {
        int sn = (s + 1 < CHL / 4) ? (s + 1) : s;
        float dl1[4], uu1[4], zz1[4];
#pragma unroll
        for (int j = 0; j < 4; j++) {
            dl1[j] = bf2f(dp[(sn * 4 + j) * DI]);
            uu1[j] = bf2f(up[(sn * 4 + j) * DI]);
            zz1[j] = bf2f(zp[(sn * 4 + j) * (2 * DI)]);
        }
#pragma unroll
        for (int j = 0; j < 4; j++) {
            int t = s * 4 + j;
            float dlt = dl0[j], uu = uu0[j], zz = zz0[j];
            float du = dlt * uu;
            float y = 0.0f;
#pragma unroll
            for (int n4 = 0; n4 < 4; n4++) {
                float4 Bv = *(const float4*)&sBC[t][n4 * 4];
                float4 Cv = *(const float4*)&sBC[t][16 + n4 * 4];
                int n = n4 * 4;
                float a0 = __expf(dlt * A[n + 0]); h[n + 0] = fmaf(a0, h[n + 0], du * Bv.x); y = fmaf(Cv.x, h[n + 0], y);
                float a1 = __expf(dlt * A[n + 1]); h[n + 1] = fmaf(a1, h[n + 1], du * Bv.y); y = fmaf(Cv.y, h[n + 1], y);
                float a2 = __expf(dlt * A[n + 2]); h[n + 2] = fmaf(a2, h[n + 2], du * Bv.z); y = fmaf(Cv.z, h[n + 2], y);
                float a3 = __expf(dlt * A[n + 3]); h[n + 3] = fmaf(a3, h[n + 3], du * Bv.w); y = fmaf(Cv.w, h[n + 3], y);
            }
            float yt = fmaf(uu, Dp, y);
            float sg = zz / (1.0f + __expf(-zz));
            gp[(size_t)t * DI] = f2bs(yt * sg);
        }
#pragma unroll
        for (int j = 0; j < 4; j++) { dl0[j] = dl1[j]; uu0[j] = uu1[j]; zz0[j] = zz1[j]; }
    }
}

// ---------- K9: head ----------
__global__ __launch_bounds__(256) void k_head(const float* h, const void* w_head, const void* b_head,
                                              void* out, const int* flag) {
    int bf = *flag;
    int wv = threadIdx.x >> 6, ln = threadIdx.x & 63;
    int row = blockIdx.x * 4 + wv;
    float4 v = *(const float4*)(h + (size_t)row * DM + ln * 4);
    float4 w = ldg4(w_head, ln * 4, bf);
    float s = v.x * w.x + v.y * w.y + v.z * w.z + v.w * w.w;
    for (int o = 1; o < 64; o <<= 1) s += __shfl_xor(s, o);
    if (ln == 0) {
        s += ldg1(b_head, 0, bf);
        if (bf) ((__hip_bfloat16*)out)[row] = __float2bfloat16(s);
        else    ((float*)out)[row] = s;
    }
}

extern "C" void kernel_launch(void* const* d_in, const int* in_sizes, int n_in,
                              void* d_out, int out_size, void* d_ws, size_t ws_size,
                              hipStream_t stream) {
    (void)in_sizes; (void)n_in; (void)out_size; (void)ws_size;
    const void* x      = d_in[0];
    const void* w_in   = d_in[1];
    const void* b_in   = d_in[2];
    const void* norm_w = d_in[3];
    const void* ipw    = d_in[4];
    const void* cw     = d_in[5];
    const void* cb     = d_in[6];
    const void* xpw    = d_in[7];
    const void* dtw    = d_in[8];
    const void* dtb    = d_in[9];
    const void* A_log  = d_in[10];
    const void* D_skip = d_in[11];
    const void* opw    = d_in[12];
    const void* w_head = d_in[13];
    const void* b_head = d_in[14];

    // workspace layout (offsets in floats)
    float* ws    = (float*)d_ws;
    float*          h     = ws;                               // f32, 4,194,304
    unsigned short* xn    = (unsigned short*)(ws + 4194304);  // bf16 (slot doubles as P/E)
    unsigned short* xz    = (unsigned short*)(ws + 8388608);  // bf16
    unsigned short* u     = (unsigned short*)(ws + 25165824); // bf16
    float*          BC    = ws + 33554432;                    // f32, 524,288 (slot 786,432)
    unsigned short* delta = (unsigned short*)(ws + 34340864); // bf16, 8,388,608 ushorts
    unsigned short* Wcomb = (unsigned short*)(ws + 38535168); // bf16, 4*576*512 = 1,179,648 ushorts
    int*            flag  = (int*)(ws + 42729472);

    float* P = (float*)xn;              // 2,097,152 f32
    float* E = (float*)xn + 2097152;    // 2,097,152 f32

    k_probe<<<1, 64, 0, stream>>>(x, flag);
    k_prep<<<NL * NF, 256, 0, stream>>>(dtw, xpw, Wcomb, flag);
    k_inproj<<<ROWS, 256, 0, stream>>>(x, w_in, b_in, h, flag);

    for (int layer = 0; layer < NL; layer++) {
        k_rmsnorm<<<ROWS / 4, 256, 0, stream>>>(h, norm_w, layer * DM, xn, flag);
        k_mfma<128, false, true><<<dim3(2 * DI / 128, ROWS / 128), 256, 0, stream>>>(
            xn, ipw, layer * 2 * DI * DM, xz, 2 * DI, DM, flag);
        k_conv<<<ROWS * DI / 256, 256, 0, stream>>>(xz, cw, cb, layer, u, flag);
        k_fused<<<dim3(NF / 64, ROWS / 128), 256, 0, stream>>>(
            u, Wcomb, layer * NF * DI, delta, BC, dtb, layer, flag);
        k_scan1<<<BATCH * NCH * 2, 256, 0, stream>>>(delta, u, BC, A_log, P, E, layer, flag);
        k_stitch<<<BATCH * DI * DS / 256, 256, 0, stream>>>(P, E);
        k_scan2<<<BATCH * NCH * 2, 256, 0, stream>>>(delta, u, BC, A_log, D_skip, xz, E,
                                                     u /*g aliases u*/, layer, flag);
        k_mfma<64, true, false><<<dim3(DM / 64, ROWS / 128), 256, 0, stream>>>(
            u, opw, layer * DM * DI, h, DM, DI, flag);
    }

    k_head<<<ROWS / 4, 256, 0, stream>>>(h, w_head, b_head, d_out, flag);
}

// Round 6
// 903.457 us; speedup vs baseline: 3.3022x; 1.0976x over previous
//
#include <hip/hip_runtime.h>
#include <hip/hip_bf16.h>

#define BATCH 8
#define SEQ   2048
#define DM    256
#define DI    512
#define DS    16
#define DTR   16
#define NL    4
#define ROWS  (BATCH*SEQ)   // 16384
#define NCH   32            // chunks for the scan
#define CHL   64            // SEQ / NCH
#define NF    576           // fused x_proj/dt GEMM width: 512 delta + 32 BC + 32 pad

typedef __attribute__((ext_vector_type(8))) __bf16 bh8;
typedef __attribute__((ext_vector_type(4))) float f4;

// ---------- dtype helpers ----------
__device__ __forceinline__ float bf2f(unsigned short u) {
    union { unsigned int i; float f; } v; v.i = ((unsigned int)u) << 16; return v.f;
}
__device__ __forceinline__ float ldg1(const void* p, int i, int bf) {
    if (bf) return bf2f(((const unsigned short*)p)[i]);
    return ((const float*)p)[i];
}
__device__ __forceinline__ float4 ldg4(const void* p, int i, int bf) { // i % 4 == 0
    if (bf) {
        ushort4 q = *(const ushort4*)(((const unsigned short*)p) + i);
        return make_float4(bf2f(q.x), bf2f(q.y), bf2f(q.z), bf2f(q.w));
    }
    return *(const float4*)(((const float*)p) + i);
}
// f32 -> bf16 bits, round-to-nearest-even
__device__ __forceinline__ unsigned short f2bs(float f) {
    union { float f; unsigned u; } x; x.f = f;
    unsigned r = (x.u + 0x7fffu + ((x.u >> 16) & 1u)) >> 16;
    return (unsigned short)r;
}

// ---------- K0: dtype probe ----------
__global__ void k_probe(const void* x, int* flag) {
    int t = threadIdx.x;  // 64 threads
    float v = bf2f(((const unsigned short*)x)[2 * t]);
    int bad = (fabsf(v) < 32.0f) ? 0 : 1;
    for (int o = 1; o < 64; o <<= 1) bad += __shfl_xor(bad, o);
    if (t == 0) *flag = (bad > 8) ? 0 : 1;  // 0 = f32, 1 = bf16
}

// ---------- K-prep: composite weight Wcomb[l][576][512] (bf16) ----------
__global__ __launch_bounds__(256) void k_prep(const void* dtw, const void* xpw,
                                              unsigned short* Wc, const int* flag) {
    int bf = *flag;
    int blk = blockIdx.x;           // 4 * 576
    int l = blk / NF, r = blk % NF;
    int t = threadIdx.x;
    unsigned short* out = Wc + ((size_t)l * NF + r) * DI;
#pragma unroll
    for (int p = 0; p < 2; p++) {
        int k = t + p * 256;
        float v = 0.0f;
        if (r < 512) {
            const int db = l * DI * DTR + r * DTR;
            const int xb = l * 48 * DI;
#pragma unroll
            for (int j = 0; j < 16; j++)
                v = fmaf(ldg1(dtw, db + j, bf), ldg1(xpw, xb + j * DI + k, bf), v);
        } else if (r < 544) {
            v = ldg1(xpw, l * 48 * DI + (16 + r - 512) * DI + k, bf);
        }
        out[k] = f2bs(v);
    }
}

// ---------- K1: input projection ----------
__global__ __launch_bounds__(256) void k_inproj(const void* x, const void* w_in,
                                                const void* b_in, float* h, const int* flag) {
    int bf = *flag;
    int row = blockIdx.x, e = threadIdx.x;
    float x0 = ldg1(x, row * 2 + 0, bf), x1 = ldg1(x, row * 2 + 1, bf);
    float w0 = ldg1(w_in, e * 2 + 0, bf), w1 = ldg1(w_in, e * 2 + 1, bf);
    float bb = ldg1(b_in, e, bf);
    h[(size_t)row * DM + e] = fmaf(x0, w0, fmaf(x1, w1, bb));
}

// ---------- K2: rmsnorm (f32 in -> bf16 out) ----------
__global__ __launch_bounds__(256) void k_rmsnorm(const float* h, const void* norm_w,
                                                 int w_off, unsigned short* xn, const int* flag) {
    int bf = *flag;
    int wv = threadIdx.x >> 6, ln = threadIdx.x & 63;
    int row = blockIdx.x * 4 + wv;
    float4 v = *(const float4*)(h + (size_t)row * DM + ln * 4);
    float ss = v.x * v.x + v.y * v.y + v.z * v.z + v.w * v.w;
    for (int o = 1; o < 64; o <<= 1) ss += __shfl_xor(ss, o);
    float sc = rsqrtf(ss / DM + 1e-5f);
    float4 w = ldg4(norm_w, w_off + ln * 4, bf);
    ushort4 o4 = { f2bs(v.x * sc * w.x), f2bs(v.y * sc * w.y),
                   f2bs(v.z * sc * w.z), f2bs(v.w * sc * w.w) };
    *(ushort4*)(xn + (size_t)row * DM + ln * 4) = o4;
}

// ---------- K3: bf16 MFMA GEMM  C[M,N] (+)= A[M,K] @ W[N,K]^T ----------
// bm = blockIdx.x (fastest): blocks sharing an A-tile revisit the same XCD -> A stays in its L2.
#define ASTR 72   // LDS row stride (ushorts): 64 + 8 pad
template <int BN, bool ADD, bool OBF>
__global__ __launch_bounds__(256, 2) void k_mfma(const unsigned short* A, const void* W, int w_off,
                                                 void* Cp, int N, int K, const int* flag) {
    int bf = *flag;
    __shared__ unsigned short As[128 * ASTR];
    __shared__ unsigned short Ws[BN * ASTR];
    constexpr int NT = BN / 32;         // col-tiles per wave
    constexpr int WCH = BN * 8 / 256;   // W staging chunks per thread

    int bm = blockIdx.x, bn = blockIdx.y;   // A-locality-major dispatch
    int t = threadIdx.x;
    int w = t >> 6, lane = t & 63;
    int wm = w >> 1, wn = w & 1;
    int lr = lane & 15, quad = lane >> 4;

    f4 acc[4][NT];
#pragma unroll
    for (int i = 0; i < 4; i++)
#pragma unroll
        for (int j = 0; j < NT; j++) acc[i][j] = f4{0.f, 0.f, 0.f, 0.f};

    for (int k0 = 0; k0 < K; k0 += 64) {
        __syncthreads();
#pragma unroll
        for (int i = 0; i < 4; i++) {
            int ch = t + i * 256;
            int r = ch >> 3, kc = (ch & 7) * 8;
            *(uint4*)&As[r * ASTR + kc] =
                *(const uint4*)(A + (size_t)(bm * 128 + r) * K + k0 + kc);
        }
#pragma unroll
        for (int i = 0; i < WCH; i++) {
            int ch = t + i * 256;
            int r = ch >> 3, kc = (ch & 7) * 8;
            size_t off = (size_t)w_off + (size_t)(bn * BN + r) * K + k0 + kc;
            if (bf) {
                *(uint4*)&Ws[r * ASTR + kc] = *(const uint4*)((const unsigned short*)W + off);
            } else {
                const float* src = (const float*)W + off;
                float4 a0 = *(const float4*)src;
                float4 a1 = *(const float4*)(src + 4);
                ushort4 v0 = { f2bs(a0.x), f2bs(a0.y), f2bs(a0.z), f2bs(a0.w) };
                ushort4 v1 = { f2bs(a1.x), f2bs(a1.y), f2bs(a1.z), f2bs(a1.w) };
                *(ushort4*)&Ws[r * ASTR + kc] = v0;
                *(ushort4*)&Ws[r * ASTR + kc + 4] = v1;
            }
        }
        __syncthreads();
#pragma unroll
        for (int ks = 0; ks < 64; ks += 32) {
            bh8 af[4];
#pragma unroll
            for (int i = 0; i < 4; i++)
                af[i] = *(const bh8*)&As[(wm * 64 + i * 16 + lr) * ASTR + ks + quad * 8];
            bh8 wf[NT];
#pragma unroll
            for (int j = 0; j < NT; j++)
                wf[j] = *(const bh8*)&Ws[(wn * (BN / 2) + j * 16 + lr) * ASTR + ks + quad * 8];
#pragma unroll
            for (int i = 0; i < 4; i++)
#pragma unroll
                for (int j = 0; j < NT; j++)
                    acc[i][j] = __builtin_amdgcn_mfma_f32_16x16x32_bf16(af[i], wf[j], acc[i][j], 0, 0, 0);
        }
    }
#pragma unroll
    for (int i = 0; i < 4; i++) {
        int row0 = bm * 128 + wm * 64 + i * 16 + quad * 4;
#pragma unroll
        for (int j = 0; j < NT; j++) {
            int col = bn * BN + wn * (BN / 2) + j * 16 + lr;
#pragma unroll
            for (int r = 0; r < 4; r++) {
                size_t idx = (size_t)(row0 + r) * N + col;
                float v = acc[i][j][r];
                if (ADD) {
                    ((float*)Cp)[idx] += v;
                } else if (OBF) {
                    ((unsigned short*)Cp)[idx] = f2bs(v);
                } else {
                    ((float*)Cp)[idx] = v;
                }
            }
        }
    }
}

// ---------- K-fused: u @ Wcomb^T -> delta (softplus, bf16) + BC (f32 [ROWS,32]) ----------
__global__ __launch_bounds__(256, 2) void k_fused(const unsigned short* A, const unsigned short* Wc,
                                                  int w_off, unsigned short* delta, float* BC,
                                                  const void* dtb, int layer, const int* flag) {
    int bf = *flag;
    __shared__ unsigned short As[128 * ASTR];
    __shared__ unsigned short Ws[64 * ASTR];

    int bm = blockIdx.x, bn = blockIdx.y;   // A-locality-major dispatch
    int t = threadIdx.x;
    int w = t >> 6, lane = t & 63;
    int wm = w >> 1, wn = w & 1;
    int lr = lane & 15, quad = lane >> 4;

    f4 acc[4][2];
#pragma unroll
    for (int i = 0; i < 4; i++)
#pragma unroll
        for (int j = 0; j < 2; j++) acc[i][j] = f4{0.f, 0.f, 0.f, 0.f};

    for (int k0 = 0; k0 < DI; k0 += 64) {
        __syncthreads();
#pragma unroll
        for (int i = 0; i < 4; i++) {
            int ch = t + i * 256;
            int r = ch >> 3, kc = (ch & 7) * 8;
            *(uint4*)&As[r * ASTR + kc] =
                *(const uint4*)(A + (size_t)(bm * 128 + r) * DI + k0 + kc);
        }
#pragma unroll
        for (int i = 0; i < 2; i++) {
            int ch = t + i * 256;
            int r = ch >> 3, kc = (ch & 7) * 8;
            *(uint4*)&Ws[r * ASTR + kc] =
                *(const uint4*)(Wc + (size_t)w_off + (size_t)(bn * 64 + r) * DI + k0 + kc);
        }
        __syncthreads();
#pragma unroll
        for (int ks = 0; ks < 64; ks += 32) {
            bh8 af[4];
#pragma unroll
            for (int i = 0; i < 4; i++)
                af[i] = *(const bh8*)&As[(wm * 64 + i * 16 + lr) * ASTR + ks + quad * 8];
            bh8 wf[2];
#pragma unroll
            for (int j = 0; j < 2; j++)
                wf[j] = *(const bh8*)&Ws[(wn * 32 + j * 16 + lr) * ASTR + ks + quad * 8];
#pragma unroll
            for (int i = 0; i < 4; i++)
#pragma unroll
                for (int j = 0; j < 2; j++)
                    acc[i][j] = __builtin_amdgcn_mfma_f32_16x16x32_bf16(af[i], wf[j], acc[i][j], 0, 0, 0);
        }
    }
#pragma unroll
    for (int i = 0; i < 4; i++) {
        int row0 = bm * 128 + wm * 64 + i * 16 + quad * 4;
#pragma unroll
        for (int j = 0; j < 2; j++) {
            int col = bn * 64 + wn * 32 + j * 16 + lr;
            if (col < 512) {
                float bb = ldg1(dtb, layer * DI + col, bf);
#pragma unroll
                for (int r = 0; r < 4; r++) {
                    float v = acc[i][j][r] + bb;
                    float sp = (v > 20.0f) ? v : log1pf(__expf(v));
                    delta[(size_t)(row0 + r) * DI + col] = f2bs(sp);
                }
            } else if (col < 544) {
#pragma unroll
                for (int r = 0; r < 4; r++)
                    BC[(size_t)(row0 + r) * 32 + (col - 512)] = acc[i][j][r];
            }
        }
    }
}

// ---------- K4: causal depthwise conv (k=4) + bias + silu  (bf16 in/out) ----------
__global__ __launch_bounds__(256) void k_conv(const unsigned short* xz, const void* cw, const void* cb,
                                              int layer, unsigned short* u, const int* flag) {
    int bf = *flag;
    int idx = blockIdx.x * 256 + threadIdx.x;  // over ROWS*DI
    int d = idx & (DI - 1);
    int row = idx >> 9;
    int l = row & (SEQ - 1);
    float4 w = ldg4(cw, (layer * DI + d) * 4, bf);
    float acc = ldg1(cb, layer * DI + d, bf);
    const unsigned short* base = xz + (size_t)row * (2 * DI) + d;
    if (l >= 3) acc = fmaf(w.x, bf2f(base[-3 * 2 * DI]), acc);
    if (l >= 2) acc = fmaf(w.y, bf2f(base[-2 * 2 * DI]), acc);
    if (l >= 1) acc = fmaf(w.z, bf2f(base[-1 * 2 * DI]), acc);
    acc = fmaf(w.w, bf2f(base[0]), acc);
    float s = acc / (1.0f + __expf(-acc));  // silu
    u[(size_t)row * DI + d] = f2bs(s);
}

// ---------- K7a: scan pass 1 ----------
__global__ __launch_bounds__(256) void k_scan1(const unsigned short* delta, const unsigned short* u,
                                               const float* BC, const void* A_log, float* P, float* E,
                                               int layer, const int* flag) {
    int bf = *flag;
    int x = blockIdx.x;                 // 512 = b(8) * c(32) * dg(2)
    int dg = x & 1, c = (x >> 1) & (NCH - 1), b = x >> 6;
    int tid = threadIdx.x;
    int d = dg * 256 + tid;
    int t0 = c * CHL;

    __shared__ float sB[CHL][16];
    {
        int r = tid >> 2, q = tid & 3;
        *(float4*)&sB[r][q * 4] =
            *(const float4*)(BC + ((size_t)b * SEQ + t0 + r) * 32 + q * 4);
    }

    float A[16];
#pragma unroll
    for (int n4 = 0; n4 < 4; n4++) {
        float4 a4 = ldg4(A_log, (layer * DI + d) * DS + n4 * 4, bf);
        A[n4 * 4 + 0] = -__expf(a4.x);
        A[n4 * 4 + 1] = -__expf(a4.y);
        A[n4 * 4 + 2] = -__expf(a4.z);
        A[n4 * 4 + 3] = -__expf(a4.w);
    }
    float h[16];
    float Pp[16];
#pragma unroll
    for (int n = 0; n < 16; n++) { h[n] = 0.0f; Pp[n] = 1.0f; }

    const unsigned short* dp = delta + ((size_t)b * SEQ + t0) * DI + d;
    const unsigned short* up = u + ((size_t)b * SEQ + t0) * DI + d;

    float dl0[4], uu0[4];
#pragma unroll
    for (int j = 0; j < 4; j++) { dl0[j] = bf2f(dp[j * DI]); uu0[j] = bf2f(up[j * DI]); }
    __syncthreads();

    for (int s = 0; s < CHL / 4; s++) {
        int sn = (s + 1 < CHL / 4) ? (s + 1) : s;     // clamped prefetch
        float dl1[4], uu1[4];
#pragma unroll
        for (int j = 0; j < 4; j++) {
            dl1[j] = bf2f(dp[(sn * 4 + j) * DI]);
            uu1[j] = bf2f(up[(sn * 4 + j) * DI]);
        }
#pragma unroll
        for (int j = 0; j < 4; j++) {
            int t = s * 4 + j;
            float dlt = dl0[j], uu = uu0[j];
            float du = dlt * uu;
#pragma unroll
            for (int n4 = 0; n4 < 4; n4++) {
                float4 Bv = *(const float4*)&sB[t][n4 * 4];
                int n = n4 * 4;
                float a0 = __expf(dlt * A[n + 0]); h[n + 0] = fmaf(a0, h[n + 0], du * Bv.x); Pp[n + 0] *= a0;
                float a1 = __expf(dlt * A[n + 1]); h[n + 1] = fmaf(a1, h[n + 1], du * Bv.y); Pp[n + 1] *= a1;
                float a2 = __expf(dlt * A[n + 2]); h[n + 2] = fmaf(a2, h[n + 2], du * Bv.z); Pp[n + 2] *= a2;
                float a3 = __expf(dlt * A[n + 3]); h[n + 3] = fmaf(a3, h[n + 3], du * Bv.w); Pp[n + 3] *= a3;
            }
        }
#pragma unroll
        for (int j = 0; j < 4; j++) { dl0[j] = dl1[j]; uu0[j] = uu1[j]; }
    }
    float* Pd = P + (((size_t)b * NCH + c) * DI + d) * DS;
    float* Ed = E + (((size_t)b * NCH + c) * DI + d) * DS;
#pragma unroll
    for (int n4 = 0; n4 < 4; n4++) {
        *(float4*)(Pd + n4 * 4) = make_float4(Pp[n4 * 4], Pp[n4 * 4 + 1], Pp[n4 * 4 + 2], Pp[n4 * 4 + 3]);
        *(float4*)(Ed + n4 * 4) = make_float4(h[n4 * 4], h[n4 * 4 + 1], h[n4 * 4 + 2], h[n4 * 4 + 3]);
    }
}

// ---------- K7b: stitch ----------
__global__ __launch_bounds__(256) void k_stitch(float* P, float* E) {
    int g = blockIdx.x * 256 + threadIdx.x;   // 65536 threads over b(8) * d(512) * n(16)
    int b = g >> 13, r = g & 8191;
    size_t base = (size_t)b * NCH * (DI * DS) + r;
    float H = 0.0f;
#pragma unroll 4
    for (int c = 0; c < NCH; c++) {
        size_t idx = base + (size_t)c * (DI * DS);
        float p = P[idx], e = E[idx];
        E[idx] = H;                 // incoming state for chunk c
        H = fmaf(p, H, e);
    }
}

// ---------- K7c: scan pass 2 ----------
__global__ __launch_bounds__(256) void k_scan2(const unsigned short* delta, const unsigned short* u,
                                               const float* BC, const void* A_log, const void* D_skip,
                                               const unsigned short* xz, const float* E,
                                               unsigned short* g, int layer, const int* flag) {
    int bf = *flag;
    int x = blockIdx.x;
    int dg = x & 1, c = (x >> 1) & (NCH - 1), b = x >> 6;
    int tid = threadIdx.x;
    int d = dg * 256 + tid;
    int t0 = c * CHL;

    __shared__ float sBC[CHL][32];   // [t][0..15]=B, [16..31]=C
#pragma unroll
    for (int k2 = 0; k2 < 2; k2++) {
        int fi = k2 * 256 + tid;
        int r = fi >> 3, q = fi & 7;
        *(float4*)&sBC[r][q * 4] =
            *(const float4*)(BC + ((size_t)b * SEQ + t0 + r) * 32 + q * 4);
    }

    float A[16];
#pragma unroll
    for (int n4 = 0; n4 < 4; n4++) {
        float4 a4 = ldg4(A_log, (layer * DI + d) * DS + n4 * 4, bf);
        A[n4 * 4 + 0] = -__expf(a4.x);
        A[n4 * 4 + 1] = -__expf(a4.y);
        A[n4 * 4 + 2] = -__expf(a4.z);
        A[n4 * 4 + 3] = -__expf(a4.w);
    }
    float Dp = ldg1(D_skip, layer * DI + d, bf);

    float h[16];
    const float* E0 = E + (((size_t)b * NCH + c) * DI + d) * DS;
#pragma unroll
    for (int n4 = 0; n4 < 4; n4++) {
        float4 h4 = *(const float4*)(E0 + n4 * 4);
        h[n4 * 4 + 0] = h4.x; h[n4 * 4 + 1] = h4.y; h[n4 * 4 + 2] = h4.z; h[n4 * 4 + 3] = h4.w;
    }

    const unsigned short* dp = delta + ((size_t)b * SEQ + t0) * DI + d;
    const unsigned short* up = u + ((size_t)b * SEQ + t0) * DI + d;
    const unsigned short* zp = xz + ((size_t)b * SEQ + t0) * (2 * DI) + DI + d;
    unsigned short* gp = g + ((size_t)b * SEQ + t0) * DI + d;

    float dl0[4], uu0[4], zz0[4];
#pragma unroll
    for (int j = 0; j < 4; j++) {
        dl0[j] = bf2f(dp[j * DI]); uu0[j] = bf2f(up[j * DI]); zz0[j] = bf2f(zp[j * (2 * DI)]);
    }
    __syncthreads();

    for (int s = 0; s < CHL / 4; s++) {
        int sn = (s + 1 < CHL / 4) ? (s + 1) : s;
        float dl1[4], uu1[4], zz1[4];
#pragma unroll
        for (int j = 0; j < 4; j++) {
            dl1[j] = bf2f(dp[(sn * 4 + j) * DI]);
            uu1[j] = bf2f(up[(sn * 4 + j) * DI]);
            zz1[j] = bf2f(zp[(sn * 4 + j) * (2 * DI)]);
        }
#pragma unroll
        for (int j = 0; j < 4; j++) {
            int t = s * 4 + j;
            float dlt = dl0[j], uu = uu0[j], zz = zz0[j];
            float du = dlt * uu;
            float y = 0.0f;
#pragma unroll
            for (int n4 = 0; n4 < 4; n4++) {
                float4 Bv = *(const float4*)&sBC[t][n4 * 4];
                float4 Cv = *(const float4*)&sBC[t][16 + n4 * 4];
                int n = n4 * 4;
                float a0 = __expf(dlt * A[n + 0]); h[n + 0] = fmaf(a0, h[n + 0], du * Bv.x); y = fmaf(Cv.x, h[n + 0], y);
                float a1 = __expf(dlt * A[n + 1]); h[n + 1] = fmaf(a1, h[n + 1], du * Bv.y); y = fmaf(Cv.y, h[n + 1], y);
                float a2 = __expf(dlt * A[n + 2]); h[n + 2] = fmaf(a2, h[n + 2], du * Bv.z); y = fmaf(Cv.z, h[n + 2], y);
                float a3 = __expf(dlt * A[n + 3]); h[n + 3] = fmaf(a3, h[n + 3], du * Bv.w); y = fmaf(Cv.w, h[n + 3], y);
            }
            float yt = fmaf(uu, Dp, y);
            float sg = zz / (1.0f + __expf(-zz));
            gp[(size_t)t * DI] = f2bs(yt * sg);
        }
#pragma unroll
        for (int j = 0; j < 4; j++) { dl0[j] = dl1[j]; uu0[j] = uu1[j]; zz0[j] = zz1[j]; }
    }
}

// ---------- K9: head ----------
__global__ __launch_bounds__(256) void k_head(const float* h, const void* w_head, const void* b_head,
                                              void* out, const int* flag) {
    int bf = *flag;
    int wv = threadIdx.x >> 6, ln = threadIdx.x & 63;
    int row = blockIdx.x * 4 + wv;
    float4 v = *(const float4*)(h + (size_t)row * DM + ln * 4);
    float4 w = ldg4(w_head, ln * 4, bf);
    float s = v.x * w.x + v.y * w.y + v.z * w.z + v.w * w.w;
    for (int o = 1; o < 64; o <<= 1) s += __shfl_xor(s, o);
    if (ln == 0) {
        s += ldg1(b_head, 0, bf);
        if (bf) ((__hip_bfloat16*)out)[row] = __float2bfloat16(s);
        else    ((float*)out)[row] = s;
    }
}

extern "C" void kernel_launch(void* const* d_in, const int* in_sizes, int n_in,
                              void* d_out, int out_size, void* d_ws, size_t ws_size,
                              hipStream_t stream) {
    (void)in_sizes; (void)n_in; (void)out_size; (void)ws_size;
    const void* x      = d_in[0];
    const void* w_in   = d_in[1];
    const void* b_in   = d_in[2];
    const void* norm_w = d_in[3];
    const void* ipw    = d_in[4];
    const void* cw     = d_in[5];
    const void* cb     = d_in[6];
    const void* xpw    = d_in[7];
    const void* dtw    = d_in[8];
    const void* dtb    = d_in[9];
    const void* A_log  = d_in[10];
    const void* D_skip = d_in[11];
    const void* opw    = d_in[12];
    const void* w_head = d_in[13];
    const void* b_head = d_in[14];

    // workspace layout (offsets in floats)
    float* ws    = (float*)d_ws;
    float*          h     = ws;                               // f32, 4,194,304
    unsigned short* xn    = (unsigned short*)(ws + 4194304);  // bf16 (slot doubles as P/E)
    unsigned short* xz    = (unsigned short*)(ws + 8388608);  // bf16
    unsigned short* u     = (unsigned short*)(ws + 25165824); // bf16
    float*          BC    = ws + 33554432;                    // f32, 524,288 (slot 786,432)
    unsigned short* delta = (unsigned short*)(ws + 34340864); // bf16, 8,388,608 ushorts
    unsigned short* Wcomb = (unsigned short*)(ws + 38535168); // bf16, 4*576*512 = 1,179,648 ushorts
    int*            flag  = (int*)(ws + 42729472);

    float* P = (float*)xn;              // 2,097,152 f32
    float* E = (float*)xn + 2097152;    // 2,097,152 f32

    k_probe<<<1, 64, 0, stream>>>(x, flag);
    k_prep<<<NL * NF, 256, 0, stream>>>(dtw, xpw, Wcomb, flag);
    k_inproj<<<ROWS, 256, 0, stream>>>(x, w_in, b_in, h, flag);

    for (int layer = 0; layer < NL; layer++) {
        k_rmsnorm<<<ROWS / 4, 256, 0, stream>>>(h, norm_w, layer * DM, xn, flag);
        k_mfma<128, false, true><<<dim3(ROWS / 128, 2 * DI / 128), 256, 0, stream>>>(
            xn, ipw, layer * 2 * DI * DM, xz, 2 * DI, DM, flag);
        k_conv<<<ROWS * DI / 256, 256, 0, stream>>>(xz, cw, cb, layer, u, flag);
        k_fused<<<dim3(ROWS / 128, NF / 64), 256, 0, stream>>>(
            u, Wcomb, layer * NF * DI, delta, BC, dtb, layer, flag);
        k_scan1<<<BATCH * NCH * 2, 256, 0, stream>>>(delta, u, BC, A_log, P, E, layer, flag);
        k_stitch<<<BATCH * DI * DS / 256, 256, 0, stream>>>(P, E);
        k_scan2<<<BATCH * NCH * 2, 256, 0, stream>>>(delta, u, BC, A_log, D_skip, xz, E,
                                                     u /*g aliases u*/, layer, flag);
        k_mfma<64, true, false><<<dim3(ROWS / 128, DM / 64), 256, 0, stream>>>(
            u, opw, layer * DM * DI, h, DM, DI, flag);
    }

    k_head<<<ROWS / 4, 256, 0, stream>>>(h, w_head, b_head, d_out, flag);
}

// Round 8
// 798.771 us; speedup vs baseline: 3.7349x; 1.1311x over previous
//
#include <hip/hip_runtime.h>
#include <hip/hip_bf16.h>

#define BATCH 8
#define SEQ   2048
#define DM    256
#define DI    512
#define DS    16
#define DTR   16
#define NL    4
#define ROWS  (BATCH*SEQ)   // 16384
#define NCH   32            // chunks for the scan
#define CHL   64            // SEQ / NCH
#define NF    576           // fused x_proj/dt GEMM width: 512 delta + 32 BC + 32 pad

typedef __attribute__((ext_vector_type(8))) __bf16 bh8;
typedef __attribute__((ext_vector_type(4))) float f4;

// ---------- dtype helpers ----------
__device__ __forceinline__ float bf2f(unsigned short u) {
    union { unsigned int i; float f; } v; v.i = ((unsigned int)u) << 16; return v.f;
}
__device__ __forceinline__ float ldg1(const void* p, int i, int bf) {
    if (bf) return bf2f(((const unsigned short*)p)[i]);
    return ((const float*)p)[i];
}
__device__ __forceinline__ float4 ldg4(const void* p, int i, int bf) { // i % 4 == 0
    if (bf) {
        ushort4 q = *(const ushort4*)(((const unsigned short*)p) + i);
        return make_float4(bf2f(q.x), bf2f(q.y), bf2f(q.z), bf2f(q.w));
    }
    return *(const float4*)(((const float*)p) + i);
}
// f32 -> bf16 bits, round-to-nearest-even
__device__ __forceinline__ unsigned short f2bs(float f) {
    union { float f; unsigned u; } x; x.f = f;
    unsigned r = (x.u + 0x7fffu + ((x.u >> 16) & 1u)) >> 16;
    return (unsigned short)r;
}
// fast silu: x * rcp(1+e^-x)  (v_rcp_f32, ~1e-5 rel err — invisible under bf16 rounding)
__device__ __forceinline__ float fsilu(float x) {
    return x * __builtin_amdgcn_rcpf(1.0f + __expf(-x));
}
// fast softplus: hw log+exp instead of libm log1pf (~25 VALU ops -> 2 transcendentals)
__device__ __forceinline__ float fsoftplus(float x) {
    return (x > 15.0f) ? x : __logf(1.0f + __expf(x));
}

// ---------- K0: dtype probe ----------
__global__ void k_probe(const void* x, int* flag) {
    int t = threadIdx.x;  // 64 threads
    float v = bf2f(((const unsigned short*)x)[2 * t]);
    int bad = (fabsf(v) < 32.0f) ? 0 : 1;
    for (int o = 1; o < 64; o <<= 1) bad += __shfl_xor(bad, o);
    if (t == 0) *flag = (bad > 8) ? 0 : 1;  // 0 = f32, 1 = bf16
}

// ---------- K-prep: composite weight Wcomb[l][576][512] (bf16) ----------
__global__ __launch_bounds__(256) void k_prep(const void* dtw, const void* xpw,
                                              unsigned short* Wc, const int* flag) {
    int bf = *flag;
    int blk = blockIdx.x;           // 4 * 576
    int l = blk / NF, r = blk % NF;
    int t = threadIdx.x;
    unsigned short* out = Wc + ((size_t)l * NF + r) * DI;
#pragma unroll
    for (int p = 0; p < 2; p++) {
        int k = t + p * 256;
        float v = 0.0f;
        if (r < 512) {
            const int db = l * DI * DTR + r * DTR;
            const int xb = l * 48 * DI;
#pragma unroll
            for (int j = 0; j < 16; j++)
                v = fmaf(ldg1(dtw, db + j, bf), ldg1(xpw, xb + j * DI + k, bf), v);
        } else if (r < 544) {
            v = ldg1(xpw, l * 48 * DI + (16 + r - 512) * DI + k, bf);
        }
        out[k] = f2bs(v);
    }
}

// ---------- K1: input projection ----------
__global__ __launch_bounds__(256) void k_inproj(const void* x, const void* w_in,
                                                const void* b_in, float* h, const int* flag) {
    int bf = *flag;
    int row = blockIdx.x, e = threadIdx.x;
    float x0 = ldg1(x, row * 2 + 0, bf), x1 = ldg1(x, row * 2 + 1, bf);
    float w0 = ldg1(w_in, e * 2 + 0, bf), w1 = ldg1(w_in, e * 2 + 1, bf);
    float bb = ldg1(b_in, e, bf);
    h[(size_t)row * DM + e] = fmaf(x0, w0, fmaf(x1, w1, bb));
}

// ---------- K2: rmsnorm (f32 in -> bf16 out) ----------
__global__ __launch_bounds__(256) void k_rmsnorm(const float* h, const void* norm_w,
                                                 int w_off, unsigned short* xn, const int* flag) {
    int bf = *flag;
    int wv = threadIdx.x >> 6, ln = threadIdx.x & 63;
    int row = blockIdx.x * 4 + wv;
    float4 v = *(const float4*)(h + (size_t)row * DM + ln * 4);
    float ss = v.x * v.x + v.y * v.y + v.z * v.z + v.w * v.w;
    for (int o = 1; o < 64; o <<= 1) ss += __shfl_xor(ss, o);
    float sc = rsqrtf(ss / DM + 1e-5f);
    float4 w = ldg4(norm_w, w_off + ln * 4, bf);
    ushort4 o4 = { f2bs(v.x * sc * w.x), f2bs(v.y * sc * w.y),
                   f2bs(v.z * sc * w.z), f2bs(v.w * sc * w.w) };
    *(ushort4*)(xn + (size_t)row * DM + ln * 4) = o4;
}

// ---------- K3: bf16 MFMA GEMM  C[M,N] (+)= A[M,K] @ W[N,K]^T ----------
// bm = blockIdx.x (fastest): A-tile locality per XCD L2.
#define ASTR 72   // LDS row stride (ushorts): 64 + 8 pad
template <int BN, bool ADD, bool OBF>
__global__ __launch_bounds__(256, 4) void k_mfma(const unsigned short* A, const void* W, int w_off,
                                                 void* Cp, int N, int K, const int* flag) {
    int bf = *flag;
    __shared__ unsigned short As[128 * ASTR];
    __shared__ unsigned short Ws[BN * ASTR];
    constexpr int NT = BN / 32;         // col-tiles per wave
    constexpr int WCH = BN * 8 / 256;   // W staging chunks per thread

    int bm = blockIdx.x, bn = blockIdx.y;
    int t = threadIdx.x;
    int w = t >> 6, lane = t & 63;
    int wm = w >> 1, wn = w & 1;
    int lr = lane & 15, quad = lane >> 4;

    f4 acc[4][NT];
#pragma unroll
    for (int i = 0; i < 4; i++)
#pragma unroll
        for (int j = 0; j < NT; j++) acc[i][j] = f4{0.f, 0.f, 0.f, 0.f};

    for (int k0 = 0; k0 < K; k0 += 64) {
        __syncthreads();
#pragma unroll
        for (int i = 0; i < 4; i++) {
            int ch = t + i * 256;
            int r = ch >> 3, kc = (ch & 7) * 8;
            *(uint4*)&As[r * ASTR + kc] =
                *(const uint4*)(A + (size_t)(bm * 128 + r) * K + k0 + kc);
        }
#pragma unroll
        for (int i = 0; i < WCH; i++) {
            int ch = t + i * 256;
            int r = ch >> 3, kc = (ch & 7) * 8;
            size_t off = (size_t)w_off + (size_t)(bn * BN + r) * K + k0 + kc;
            if (bf) {
                *(uint4*)&Ws[r * ASTR + kc] = *(const uint4*)((const unsigned short*)W + off);
            } else {
                const float* src = (const float*)W + off;
                float4 a0 = *(const float4*)src;
                float4 a1 = *(const float4*)(src + 4);
                ushort4 v0 = { f2bs(a0.x), f2bs(a0.y), f2bs(a0.z), f2bs(a0.w) };
                ushort4 v1 = { f2bs(a1.x), f2bs(a1.y), f2bs(a1.z), f2bs(a1.w) };
                *(ushort4*)&Ws[r * ASTR + kc] = v0;
                *(ushort4*)&Ws[r * ASTR + kc + 4] = v1;
            }
        }
        __syncthreads();
#pragma unroll
        for (int ks = 0; ks < 64; ks += 32) {
            bh8 af[4];
#pragma unroll
            for (int i = 0; i < 4; i++)
                af[i] = *(const bh8*)&As[(wm * 64 + i * 16 + lr) * ASTR + ks + quad * 8];
            bh8 wf[NT];
#pragma unroll
            for (int j = 0; j < NT; j++)
                wf[j] = *(const bh8*)&Ws[(wn * (BN / 2) + j * 16 + lr) * ASTR + ks + quad * 8];
#pragma unroll
            for (int i = 0; i < 4; i++)
#pragma unroll
                for (int j = 0; j < NT; j++)
                    acc[i][j] = __builtin_amdgcn_mfma_f32_16x16x32_bf16(af[i], wf[j], acc[i][j], 0, 0, 0);
        }
    }
#pragma unroll
    for (int i = 0; i < 4; i++) {
        int row0 = bm * 128 + wm * 64 + i * 16 + quad * 4;
#pragma unroll
        for (int j = 0; j < NT; j++) {
            int col = bn * BN + wn * (BN / 2) + j * 16 + lr;
#pragma unroll
            for (int r = 0; r < 4; r++) {
                size_t idx = (size_t)(row0 + r) * N + col;
                float v = acc[i][j][r];
                if (ADD) {
                    ((float*)Cp)[idx] += v;
                } else if (OBF) {
                    ((unsigned short*)Cp)[idx] = f2bs(v);
                } else {
                    ((float*)Cp)[idx] = v;
                }
            }
        }
    }
}

// ---------- K-fused: u @ Wcomb^T -> delta (softplus, bf16) + BC (f32 [ROWS,32]) ----------
__global__ __launch_bounds__(256, 4) void k_fused(const unsigned short* A, const unsigned short* Wc,
                                                  int w_off, unsigned short* delta, float* BC,
                                                  const void* dtb, int layer, const int* flag) {
    int bf = *flag;
    __shared__ unsigned short As[128 * ASTR];
    __shared__ unsigned short Ws[64 * ASTR];

    int bm = blockIdx.x, bn = blockIdx.y;
    int t = threadIdx.x;
    int w = t >> 6, lane = t & 63;
    int wm = w >> 1, wn = w & 1;
    int lr = lane & 15, quad = lane >> 4;

    f4 acc[4][2];
#pragma unroll
    for (int i = 0; i < 4; i++)
#pragma unroll
        for (int j = 0; j < 2; j++) acc[i][j] = f4{0.f, 0.f, 0.f, 0.f};

    for (int k0 = 0; k0 < DI; k0 += 64) {
        __syncthreads();
#pragma unroll
        for (int i = 0; i < 4; i++) {
            int ch = t + i * 256;
            int r = ch >> 3, kc = (ch & 7) * 8;
            *(uint4*)&As[r * ASTR + kc] =
                *(const uint4*)(A + (size_t)(bm * 128 + r) * DI + k0 + kc);
        }
#pragma unroll
        for (int i = 0; i < 2; i++) {
            int ch = t + i * 256;
            int r = ch >> 3, kc = (ch & 7) * 8;
            *(uint4*)&Ws[r * ASTR + kc] =
                *(const uint4*)(Wc + (size_t)w_off + (size_t)(bn * 64 + r) * DI + k0 + kc);
        }
        __syncthreads();
#pragma unroll
        for (int ks = 0; ks < 64; ks += 32) {
            bh8 af[4];
#pragma unroll
            for (int i = 0; i < 4; i++)
                af[i] = *(const bh8*)&As[(wm * 64 + i * 16 + lr) * ASTR + ks + quad * 8];
            bh8 wf[2];
#pragma unroll
            for (int j = 0; j < 2; j++)
                wf[j] = *(const bh8*)&Ws[(wn * 32 + j * 16 + lr) * ASTR + ks + quad * 8];
#pragma unroll
            for (int i = 0; i < 4; i++)
#pragma unroll
                for (int j = 0; j < 2; j++)
                    acc[i][j] = __builtin_amdgcn_mfma_f32_16x16x32_bf16(af[i], wf[j], acc[i][j], 0, 0, 0);
        }
    }
#pragma unroll
    for (int i = 0; i < 4; i++) {
        int row0 = bm * 128 + wm * 64 + i * 16 + quad * 4;
#pragma unroll
        for (int j = 0; j < 2; j++) {
            int col = bn * 64 + wn * 32 + j * 16 + lr;
            if (col < 512) {
                float bb = ldg1(dtb, layer * DI + col, bf);
#pragma unroll
                for (int r = 0; r < 4; r++) {
                    float v = acc[i][j][r] + bb;
                    delta[(size_t)(row0 + r) * DI + col] = f2bs(fsoftplus(v));
                }
            } else if (col < 544) {
#pragma unroll
                for (int r = 0; r < 4; r++)
                    BC[(size_t)(row0 + r) * 32 + (col - 512)] = acc[i][j][r];
            }
        }
    }
}

// ---------- K4: causal depthwise conv (k=4) + bias + silu  (bf16 in/out) ----------
__global__ __launch_bounds__(256) void k_conv(const unsigned short* xz, const void* cw, const void* cb,
                                              int layer, unsigned short* u, const int* flag) {
    int bf = *flag;
    int idx = blockIdx.x * 256 + threadIdx.x;  // over ROWS*DI
    int d = idx & (DI - 1);
    int row = idx >> 9;
    int l = row & (SEQ - 1);
    float4 w = ldg4(cw, (layer * DI + d) * 4, bf);
    float acc = ldg1(cb, layer * DI + d, bf);
    const unsigned short* base = xz + (size_t)row * (2 * DI) + d;
    if (l >= 3) acc = fmaf(w.x, bf2f(base[-3 * 2 * DI]), acc);
    if (l >= 2) acc = fmaf(w.y, bf2f(base[-2 * 2 * DI]), acc);
    if (l >= 1) acc = fmaf(w.z, bf2f(base[-1 * 2 * DI]), acc);
    acc = fmaf(w.w, bf2f(base[0]), acc);
    u[(size_t)row * DI + d] = f2bs(fsilu(acc));
}

// ---------- K7a: scan pass 1 ----------
__global__ __launch_bounds__(256) void k_scan1(const unsigned short* delta, const unsigned short* u,
                                               const float* BC, const void* A_log, float* P, float* E,
                                               int layer, const int* flag) {
    int bf = *flag;
    int x = blockIdx.x;                 // 512 = b(8) * c(32) * dg(2)
    int dg = x & 1, c = (x >> 1) & (NCH - 1), b = x >> 6;
    int tid = threadIdx.x;
    int d = dg * 256 + tid;
    int t0 = c * CHL;

    __shared__ float sB[CHL][16];
    {
        int r = tid >> 2, q = tid & 3;
        *(float4*)&sB[r][q * 4] =
            *(const float4*)(BC + ((size_t)b * SEQ + t0 + r) * 32 + q * 4);
    }

    float A[16];
#pragma unroll
    for (int n4 = 0; n4 < 4; n4++) {
        float4 a4 = ldg4(A_log, (layer * DI + d) * DS + n4 * 4, bf);
        A[n4 * 4 + 0] = -__expf(a4.x);
        A[n4 * 4 + 1] = -__expf(a4.y);
        A[n4 * 4 + 2] = -__expf(a4.z);
        A[n4 * 4 + 3] = -__expf(a4.w);
    }
    float h[16];
    float Pp[16];
#pragma unroll
    for (int n = 0; n < 16; n++) { h[n] = 0.0f; Pp[n] = 1.0f; }

    const unsigned short* dp = delta + ((size_t)b * SEQ + t0) * DI + d;
    const unsigned short* up = u + ((size_t)b * SEQ + t0) * DI + d;

    float dl0[4], uu0[4];
#pragma unroll
    for (int j = 0; j < 4; j++) { dl0[j] = bf2f(dp[j * DI]); uu0[j] = bf2f(up[j * DI]); }
    __syncthreads();

    for (int s = 0; s < CHL / 4; s++) {
        int sn = (s + 1 < CHL / 4) ? (s + 1) : s;     // clamped prefetch
        float dl1[4], uu1[4];
#pragma unroll
        for (int j = 0; j < 4; j++) {
            dl1[j] = bf2f(dp[(sn * 4 + j) * DI]);
            uu1[j] = bf2f(up[(sn * 4 + j) * DI]);
        }
#pragma unroll
        for (int j = 0; j < 4; j++) {
            int t = s * 4 + j;
            float dlt = dl0[j], uu = uu0[j];
            float du = dlt * uu;
#pragma unroll
            for (int n4 = 0; n4 < 4; n4++) {
                float4 Bv = *(const float4*)&sB[t][n4 * 4];
                int n = n4 * 4;
                float a0 = __expf(dlt * A[n + 0]); h[n + 0] = fmaf(a0, h[n + 0], du * Bv.x); Pp[n + 0] *= a0;
                float a1 = __expf(dlt * A[n + 1]); h[n + 1] = fmaf(a1, h[n + 1], du * Bv.y); Pp[n + 1] *= a1;
                float a2 = __expf(dlt * A[n + 2]); h[n + 2] = fmaf(a2, h[n + 2], du * Bv.z); Pp[n + 2] *= a2;
                float a3 = __expf(dlt * A[n + 3]); h[n + 3] = fmaf(a3, h[n + 3], du * Bv.w); Pp[n + 3] *= a3;
            }
        }
#pragma unroll
        for (int j = 0; j < 4; j++) { dl0[j] = dl1[j]; uu0[j] = uu1[j]; }
    }
    float* Pd = P + (((size_t)b * NCH + c) * DI + d) * DS;
    float* Ed = E + (((size_t)b * NCH + c) * DI + d) * DS;
#pragma unroll
    for (int n4 = 0; n4 < 4; n4++) {
        *(float4*)(Pd + n4 * 4) = make_float4(Pp[n4 * 4], Pp[n4 * 4 + 1], Pp[n4 * 4 + 2], Pp[n4 * 4 + 3]);
        *(float4*)(Ed + n4 * 4) = make_float4(h[n4 * 4], h[n4 * 4 + 1], h[n4 * 4 + 2], h[n4 * 4 + 3]);
    }
}

// ---------- K7b: stitch ----------
__global__ __launch_bounds__(256) void k_stitch(float* P, float* E) {
    int g = blockIdx.x * 256 + threadIdx.x;   // 65536 threads over b(8) * d(512) * n(16)
    int b = g >> 13, r = g & 8191;
    size_t base = (size_t)b * NCH * (DI * DS) + r;
    float H = 0.0f;
#pragma unroll 4
    for (int c = 0; c < NCH; c++) {
        size_t idx = base + (size_t)c * (DI * DS);
        float p = P[idx], e = E[idx];
        E[idx] = H;                 // incoming state for chunk c
        H = fmaf(p, H, e);
    }
}

// ---------- K7c: scan pass 2 ----------
__global__ __launch_bounds__(256) void k_scan2(const unsigned short* delta, const unsigned short* u,
                                               const float* BC, const void* A_log, const void* D_skip,
                                               const unsigned short* xz, const float* E,
                                               unsigned short* g, int layer, const int* flag) {
    int bf = *flag;
    int x = blockIdx.x;
    int dg = x & 1, c = (x >> 1) & (NCH - 1), b = x >> 6;
    int tid = threadIdx.x;
    int d = dg * 256 + tid;
    int t0 = c * CHL;

    __shared__ float sBC[CHL][32];   // [t][0..15]=B, [16..31]=C
#pragma unroll
    for (int k2 = 0; k2 < 2; k2++) {
        int fi = k2 * 256 + tid;
        int r = fi >> 3, q = fi & 7;
        *(float4*)&sBC[r][q * 4] =
            *(const float4*)(BC + ((size_t)b * SEQ + t0 + r) * 32 + q * 4);
    }

    float A[16];
#pragma unroll
    for (int n4 = 0; n4 < 4; n4++) {
        float4 a4 = ldg4(A_log, (layer * DI + d) * DS + n4 * 4, bf);
        A[n4 * 4 + 0] = -__expf(a4.x);
        A[n4 * 4 + 1] = -__expf(a4.y);
        A[n4 * 4 + 2] = -__expf(a4.z);
        A[n4 * 4 + 3] = -__expf(a4.w);
    }
    float Dp = ldg1(D_skip, layer * DI + d, bf);

    float h[16];
    const float* E0 = E + (((size_t)b * NCH + c) * DI + d) * DS;
#pragma unroll
    for (int n4 = 0; n4 < 4; n4++) {
        float4 h4 = *(const float4*)(E0 + n4 * 4);
        h[n4 * 4 + 0] = h4.x; h[n4 * 4 + 1] = h4.y; h[n4 * 4 + 2] = h4.z; h[n4 * 4 + 3] = h4.w;
    }

    const unsigned short* dp = delta + ((size_t)b * SEQ + t0) * DI + d;
    const unsigned short* up = u + ((size_t)b * SEQ + t0) * DI + d;
    const unsigned short* zp = xz + ((size_t)b * SEQ + t0) * (2 * DI) + DI + d;
    unsigned short* gp = g + ((size_t)b * SEQ + t0) * DI + d;

    float dl0[4], uu0[4], zz0[4];
#pragma unroll
    for (int j = 0; j < 4; j++) {
        dl0[j] = bf2f(dp[j * DI]); uu0[j] = bf2f(up[j * DI]); zz0[j] = bf2f(zp[j * (2 * DI)]);
    }
    __syncthreads();

    for (int s = 0; s < CHL / 4; s++) {
        int sn = (s + 1 < CHL / 4) ? (s + 1) : s;
        float dl1[4], uu1[4], zz1[4];
#pragma unroll
        for (int j = 0; j < 4; j++) {
            dl1[j] = bf2f(dp[(sn * 4 + j) * DI]);
            uu1[j] = bf2f(up[(sn * 4 + j) * DI]);
            zz1[j] = bf2f(zp[(sn * 4 + j) * (2 * DI)]);
        }
#pragma unroll
        for (int j = 0; j < 4; j++) {
            int t = s * 4 + j;
            float dlt = dl0[j], uu = uu0[j], zz = zz0[j];
            float du = dlt * uu;
            float y = 0.0f;
#pragma unroll
            for (int n4 = 0; n4 < 4; n4++) {
                float4 Bv = *(const float4*)&sBC[t][n4 * 4];
                float4 Cv = *(const float4*)&sBC[t][16 + n4 * 4];
                int n = n4 * 4;
                float a0 = __expf(dlt * A[n + 0]); h[n + 0] = fmaf(a0, h[n + 0], du * Bv.x); y = fmaf(Cv.x, h[n + 0], y);
                float a1 = __expf(dlt * A[n + 1]); h[n + 1] = fmaf(a1, h[n + 1], du * Bv.y); y = fmaf(Cv.y, h[n + 1], y);
                float a2 = __expf(dlt * A[n + 2]); h[n + 2] = fmaf(a2, h[n + 2], du * Bv.z); y = fmaf(Cv.z, h[n + 2], y);
                float a3 = __expf(dlt * A[n + 3]); h[n + 3] = fmaf(a3, h[n + 3], du * Bv.w); y = fmaf(Cv.w, h[n + 3], y);
            }
            float yt = fmaf(uu, Dp, y);
            gp[(size_t)t * DI] = f2bs(yt * fsilu(zz));
        }
#pragma unroll
        for (int j = 0; j < 4; j++) { dl0[j] = dl1[j]; uu0[j] = uu1[j]; zz0[j] = zz1[j]; }
    }
}

// ---------- K9: head ----------
__global__ __launch_bounds__(256) void k_head(const float* h, const void* w_head, const void* b_head,
                                              void* out, const int* flag) {
    int bf = *flag;
    int wv = threadIdx.x >> 6, ln = threadIdx.x & 63;
    int row = blockIdx.x * 4 + wv;
    float4 v = *(const float4*)(h + (size_t)row * DM + ln * 4);
    float4 w = ldg4(w_head, ln * 4, bf);
    float s = v.x * w.x + v.y * w.y + v.z * w.z + v.w * w.w;
    for (int o = 1; o < 64; o <<= 1) s += __shfl_xor(s, o);
    if (ln == 0) {
        s += ldg1(b_head, 0, bf);
        if (bf) ((__hip_bfloat16*)out)[row] = __float2bfloat16(s);
        else    ((float*)out)[row] = s;
    }
}

extern "C" void kernel_launch(void* const* d_in, const int* in_sizes, int n_in,
                              void* d_out, int out_size, void* d_ws, size_t ws_size,
                              hipStream_t stream) {
    (void)in_sizes; (void)n_in; (void)out_size; (void)ws_size;
    const void* x      = d_in[0];
    const void* w_in   = d_in[1];
    const void* b_in   = d_in[2];
    const void* norm_w = d_in[3];
    const void* ipw    = d_in[4];
    const void* cw     = d_in[5];
    const void* cb     = d_in[6];
    const void* xpw    = d_in[7];
    const void* dtw    = d_in[8];
    const void* dtb    = d_in[9];
    const void* A_log  = d_in[10];
    const void* D_skip = d_in[11];
    const void* opw    = d_in[12];
    const void* w_head = d_in[13];
    const void* b_head = d_in[14];

    // workspace layout (offsets in floats)
    float* ws    = (float*)d_ws;
    float*          h     = ws;                               // f32, 4,194,304
    unsigned short* xn    = (unsigned short*)(ws + 4194304);  // bf16 (slot doubles as P/E)
    unsigned short* xz    = (unsigned short*)(ws + 8388608);  // bf16
    unsigned short* u     = (unsigned short*)(ws + 25165824); // bf16
    float*          BC    = ws + 33554432;                    // f32, 524,288 (slot 786,432)
    unsigned short* delta = (unsigned short*)(ws + 34340864); // bf16, 8,388,608 ushorts
    unsigned short* Wcomb = (unsigned short*)(ws + 38535168); // bf16, 4*576*512 = 1,179,648 ushorts
    int*            flag  = (int*)(ws + 42729472);

    float* P = (float*)xn;              // 2,097,152 f32
    float* E = (float*)xn + 2097152;    // 2,097,152 f32

    k_probe<<<1, 64, 0, stream>>>(x, flag);
    k_prep<<<NL * NF, 256, 0, stream>>>(dtw, xpw, Wcomb, flag);
    k_inproj<<<ROWS, 256, 0, stream>>>(x, w_in, b_in, h, flag);

    for (int layer = 0; layer < NL; layer++) {
        k_rmsnorm<<<ROWS / 4, 256, 0, stream>>>(h, norm_w, layer * DM, xn, flag);
        k_mfma<128, false, true><<<dim3(ROWS / 128, 2 * DI / 128), 256, 0, stream>>>(
            xn, ipw, layer * 2 * DI * DM, xz, 2 * DI, DM, flag);
        k_conv<<<ROWS * DI / 256, 256, 0, stream>>>(xz, cw, cb, layer, u, flag);
        k_fused<<<dim3(ROWS / 128, NF / 64), 256, 0, stream>>>(
            u, Wcomb, layer * NF * DI, delta, BC, dtb, layer, flag);
        k_scan1<<<BATCH * NCH * 2, 256, 0, stream>>>(delta, u, BC, A_log, P, E, layer, flag);
        k_stitch<<<BATCH * DI * DS / 256, 256, 0, stream>>>(P, E);
        k_scan2<<<BATCH * NCH * 2, 256, 0, stream>>>(delta, u, BC, A_log, D_skip, xz, E,
                                                     u /*g aliases u*/, layer, flag);
        k_mfma<64, true, false><<<dim3(ROWS / 128, DM / 64), 256, 0, stream>>>(
            u, opw, layer * DM * DI, h, DM, DI, flag);
    }

    k_head<<<ROWS / 4, 256, 0, stream>>>(h, w_head, b_head, d_out, flag);
}